// Round 11
// baseline (2560.420 us; speedup 1.0000x reference)
//
#include <hip/hip_runtime.h>

static constexpr int BLK = 256;

typedef double d2 __attribute__((ext_vector_type(2)));
typedef int    i4 __attribute__((ext_vector_type(4)));

__device__ __forceinline__ double gelu_d(double v){
  double u = 0.7978845608028654 * (v + 0.044715 * v * v * v);
  return 0.5 * v * (1.0 + tanh(u));
}

__global__ void zero_k(int* __restrict__ a, int n){
  int stride = gridDim.x * blockDim.x;
  for (int i = blockIdx.x*blockDim.x + threadIdx.x; i < n; i += stride) a[i] = 0;
}

__global__ void zeromax_k(unsigned long long* m){
  if (threadIdx.x == 0 && blockIdx.x == 0){
    m[0] = 0ull; m[1] = 0ull; m[2] = 0ull; m[3] = 0ull;
  }
}

// ---- edge dtype probe ----
__global__ void detect_k(const int* __restrict__ ei, int* __restrict__ flag){
  if (threadIdx.x == 0 && blockIdx.x == 0){
    int zeros = 0;
    for (int i = 0; i < 64; ++i) if (ei[2*i + 1] == 0) ++zeros;
    *flag = (zeros >= 48) ? 1 : 0;
  }
}

__global__ void count_k(const int* __restrict__ ei, int E, const int* __restrict__ flag,
                        int* __restrict__ cnt){
  int is64 = *flag;
  int stride = gridDim.x * blockDim.x;
  for (int e = blockIdx.x*blockDim.x + threadIdx.x; e < E; e += stride){
    int d = is64 ? ei[2*(E + e)] : ei[E + e];
    atomicAdd(&cnt[d], 1);
  }
}

__global__ void dinv_k(const int* __restrict__ cnt, double* __restrict__ dinv, int n){
  int i = blockIdx.x*blockDim.x + threadIdx.x;
  if (i < n){
    double deg = (double)(cnt[i] + 1);
    dinv[i] = 1.0 / sqrt(deg);
  }
}

__global__ __launch_bounds__(256)
void scanA_k(const int* __restrict__ cnt, int* __restrict__ partial, int n, int chunk){
  __shared__ int red[256];
  int b = blockIdx.x;
  int lo = b * chunk, hi = min(n, lo + chunk);
  int s = 0;
  for (int i = lo + threadIdx.x; i < hi; i += 256) s += cnt[i];
  red[threadIdx.x] = s; __syncthreads();
  for (int off = 128; off > 0; off >>= 1){
    if (threadIdx.x < off) red[threadIdx.x] += red[threadIdx.x + off];
    __syncthreads();
  }
  if (threadIdx.x == 0) partial[b] = red[0];
}

__global__ __launch_bounds__(256)
void scanB_k(int* __restrict__ partial, int nb){
  __shared__ int sd[256];
  int tid = threadIdx.x;
  int v = (tid < nb) ? partial[tid] : 0;
  sd[tid] = v; __syncthreads();
  for (int off = 1; off < 256; off <<= 1){
    int t = (tid >= off) ? sd[tid - off] : 0;
    __syncthreads();
    sd[tid] += t;
    __syncthreads();
  }
  if (tid < nb) partial[tid] = sd[tid] - v;
  if (tid == 255) partial[nb] = sd[255];
}

__global__ __launch_bounds__(256)
void scanC_k(const int* __restrict__ cnt, const int* __restrict__ partial,
             int* __restrict__ rp, int n, int chunk, int nb){
  __shared__ int sd[256];
  int b = blockIdx.x;
  int lo = b * chunk, hi = min(n, lo + chunk);
  int run = partial[b];
  for (int base = lo; base < hi; base += 256){
    int i = base + threadIdx.x;
    int v = (i < hi) ? cnt[i] : 0;
    sd[threadIdx.x] = v; __syncthreads();
    for (int off = 1; off < 256; off <<= 1){
      int t = (threadIdx.x >= off) ? sd[threadIdx.x - off] : 0;
      __syncthreads();
      sd[threadIdx.x] += t;
      __syncthreads();
    }
    if (i < hi) rp[i] = run + sd[threadIdx.x] - v;
    run += sd[255];
    __syncthreads();
  }
  if (b == 0 && threadIdx.x == 0) rp[n] = partial[nb];
}

__global__ void scatter_k(const int* __restrict__ ei, int E, const int* __restrict__ flag,
                          const int* __restrict__ rp, int* __restrict__ fill,
                          const double* __restrict__ dinv,
                          int* __restrict__ col, double* __restrict__ val){
  int is64 = *flag;
  int stride = gridDim.x * blockDim.x;
  for (int e = blockIdx.x*blockDim.x + threadIdx.x; e < E; e += stride){
    int s = is64 ? ei[2*e]       : ei[e];
    int d = is64 ? ei[2*(E + e)] : ei[E + e];
    int p = rp[d] + atomicAdd(&fill[d], 1);
    col[p] = s;
    if (val) val[p] = dinv[s];
  }
}

template<typename ST>
__global__ void concat_k(const float* __restrict__ x, const float* __restrict__ t,
                         ST* __restrict__ h0, int n){
  int total = n * 66;
  int stride = gridDim.x * blockDim.x;
  for (int idx = blockIdx.x*blockDim.x + threadIdx.x; idx < total; idx += stride){
    int row = idx / 66;
    int c = idx - row * 66;
    float v = (c < 64) ? x[row*64 + c] : (c == 64 ? t[row] : 0.0f);
    h0[idx] = (ST)v;
  }
}

// ================== f64 VALU GEMM (round-9 state, + optional absmax) ==========
template<typename ST>
__global__ __launch_bounds__(256, 4)
void gemm_k(const ST* __restrict__ A, int K, int lda,
            const float* __restrict__ W, int NOUT,
            const float* __restrict__ bias,
            ST* __restrict__ C, float* __restrict__ Cf,
            int n, int fuse, unsigned long long* __restrict__ amax)
{
  __shared__ __align__(16) double As[128][18];
  __shared__ __align__(16) double Ws[16][66];
  const int row0 = blockIdx.x * 128;
  const int col0 = blockIdx.y * 64;
  const int tid = threadIdx.x;
  const int tr = tid >> 4, tc = tid & 15;
  const int c0 = 2 * tc;
  double acc[8][4] = {};

  const int sar = tid >> 1;
  const int sak = (tid & 1) * 8;
  const int swr = tid >> 4;
  const int swc = (tid & 15) * 4;

  const int ktiles = (K + 15) / 16;

  double ga[8];
  float  gw[4];

  auto loadA = [&](int k0){
    int gr = row0 + sar;
    if constexpr (sizeof(ST) == 8){
      if (gr < n){
        const double* Ap = (const double*)A + (size_t)gr * lda + k0 + sak;
        #pragma unroll
        for (int g = 0; g < 4; ++g){
          d2 v = *(const d2*)(Ap + 2*g);
          ga[2*g] = v.x; ga[2*g+1] = v.y;
        }
      } else {
        #pragma unroll
        for (int u = 0; u < 8; ++u) ga[u] = 0.0;
      }
    } else {
      const ST* Ap = A + (size_t)gr * lda + k0 + sak;
      #pragma unroll
      for (int u = 0; u < 8; ++u){
        int kg = k0 + sak + u;
        ga[u] = (gr < n && kg < K) ? (double)Ap[u] : 0.0;
      }
    }
  };
  auto loadW = [&](int k0){
    int kg = k0 + swr;
    if (kg < K){
      const float* Wp = W + (size_t)kg * NOUT + col0 + swc;
      #pragma unroll
      for (int g = 0; g < 4; ++g) gw[g] = Wp[g];
    } else {
      #pragma unroll
      for (int g = 0; g < 4; ++g) gw[g] = 0.0f;
    }
  };

  loadA(0);
  loadW(0);

  for (int kt = 0; kt < ktiles; ++kt){
    #pragma unroll
    for (int g = 0; g < 4; ++g){
      d2 v; v.x = ga[2*g]; v.y = ga[2*g+1];
      *(d2*)&As[sar][sak + 2*g] = v;
    }
    {
      d2 v0; v0.x = (double)gw[0]; v0.y = (double)gw[1];
      d2 v1; v1.x = (double)gw[2]; v1.y = (double)gw[3];
      *(d2*)&Ws[swr][swc]     = v0;
      *(d2*)&Ws[swr][swc + 2] = v1;
    }
    __syncthreads();
    if (kt + 1 < ktiles){
      loadA((kt + 1) * 16);
      loadW((kt + 1) * 16);
    }
    #pragma unroll
    for (int kk = 0; kk < 16; kk += 2){
      d2 w0a = *(const d2*)&Ws[kk    ][c0];
      d2 w0b = *(const d2*)&Ws[kk    ][c0 + 32];
      d2 w1a = *(const d2*)&Ws[kk + 1][c0];
      d2 w1b = *(const d2*)&Ws[kk + 1][c0 + 32];
      #pragma unroll
      for (int i = 0; i < 8; ++i){
        d2 av = *(const d2*)&As[tr + 16*i][kk];
        acc[i][0] = fma(av.x, w0a.x, acc[i][0]);
        acc[i][1] = fma(av.x, w0a.y, acc[i][1]);
        acc[i][2] = fma(av.x, w0b.x, acc[i][2]);
        acc[i][3] = fma(av.x, w0b.y, acc[i][3]);
        acc[i][0] = fma(av.y, w1a.x, acc[i][0]);
        acc[i][1] = fma(av.y, w1a.y, acc[i][1]);
        acc[i][2] = fma(av.y, w1b.x, acc[i][2]);
        acc[i][3] = fma(av.y, w1b.y, acc[i][3]);
      }
    }
    __syncthreads();
  }
  double tmax = 0.0;
  #pragma unroll
  for (int i = 0; i < 8; ++i){
    int r = row0 + tr + 16*i;
    if (r >= n) continue;
    #pragma unroll
    for (int j = 0; j < 4; ++j){
      int c = col0 + ((j < 2) ? (c0 + j) : (c0 + 30 + j));
      double v = acc[i][j];
      if (fuse){ v += (double)bias[c]; if (fuse == 1) v = gelu_d(v); }
      if (amax) tmax = fmax(tmax, fabs(v));
      if (fuse == 2) __builtin_nontemporal_store((float)v, &Cf[(size_t)r * NOUT + c]);
      else           __builtin_nontemporal_store((ST)v,   &C [(size_t)r * NOUT + c]);
    }
  }
  if (amax){
    #pragma unroll
    for (int off = 32; off > 0; off >>= 1)
      tmax = fmax(tmax, __shfl_xor(tmax, off));
    if ((threadIdx.x & 63) == 0)
      atomicMax(amax, (unsigned long long)__double_as_longlong(tmax));
  }
}

// ================== Ozaki int8-MFMA exact GEMM =================================
// C[n x 128] = A[n x 256](f64) @ W[256 x 128](f32), fp64-accurate via 5 signed
// radix-256 digit planes + i32 MFMA (exact). A quantized IN-KERNEL to LDS
// (no global digit buffer). Pairs p+q<=1 dropped (contribution < 1e-13 rel).

__global__ void absmaxW_k(const float* __restrict__ W, int n, unsigned long long* __restrict__ out){
  double tmax = 0.0;
  int stride = gridDim.x * blockDim.x;
  for (int i = blockIdx.x*blockDim.x + threadIdx.x; i < n; i += stride)
    tmax = fmax(tmax, (double)fabsf(W[i]));
  #pragma unroll
  for (int off = 32; off > 0; off >>= 1)
    tmax = fmax(tmax, __shfl_xor(tmax, off));
  if ((threadIdx.x & 63) == 0)
    atomicMax(out, (unsigned long long)__double_as_longlong(tmax));
}

// W[K][N] f32 -> WqT[5][N][K] i8  (K=256, N=128)
__global__ void quantW_k(const float* __restrict__ W, int K, int N,
                         const unsigned long long* __restrict__ maxw,
                         char* __restrict__ WqT){
  double wm = __longlong_as_double((long long)*maxw);
  int sw = (wm > 0.0) ? (37 - ilogb(wm)) : 0;
  double sc = ldexp(1.0, sw);
  int total = K * N;
  size_t NK = (size_t)N * K;
  int stride = gridDim.x * blockDim.x;
  for (int t = blockIdx.x*blockDim.x + threadIdx.x; t < total; t += stride){
    int k = t / N, nn = t - k * N;
    long long v = __double2ll_rn((double)W[t] * sc);
    #pragma unroll
    for (int p = 0; p < 5; ++p){
      int d = (int)((v + 128) & 255) - 128;
      WqT[(size_t)p * NK + (size_t)nn * K + k] = (char)d;
      v = (v - d) >> 8;
    }
  }
}

// block: 512 thr = 8 waves; wave ct -> cols [16ct,16ct+16); block rows [16b,16b+16)
// fuse: 0 = raw f64 C ; 1 = +bias, gelu -> f64 C
__global__ __launch_bounds__(512)
void ozaki_k(const double* __restrict__ A, const char* __restrict__ WqT,
             const unsigned long long* __restrict__ maxa,
             const unsigned long long* __restrict__ maxw,
             const float* __restrict__ bias,
             double* __restrict__ C, int n, int fuse)
{
  constexpr int K = 256, N = 128;
  constexpr int PP[22] = {0,0,0, 1,1,1,1, 2,2,2,2,2, 3,3,3,3,3, 4,4,4,4,4};
  constexpr int QQ[22] = {2,3,4, 1,2,3,4, 0,1,2,3,4, 0,1,2,3,4, 0,1,2,3,4};
  __shared__ __align__(16) char laq[5][16][272];   // [plane][row][k], 272=17*16 pad
  const int tid  = threadIdx.x;
  const int lane = tid & 63;
  const int ct   = tid >> 6;          // wave id = col-tile
  const int l15  = lane & 15;
  const int lk   = lane >> 4;         // 0..3
  const int row0 = blockIdx.x * 16;

  double am = __longlong_as_double((long long)*maxa);
  double wm = __longlong_as_double((long long)*maxw);
  int sa = (am > 0.0) ? (38 - ilogb(am)) : 0;
  int sw = (wm > 0.0) ? (37 - ilogb(wm)) : 0;
  double sc = ldexp(1.0, sa);

  { // in-kernel quantization: 16 rows x 256 k; thread -> row tid>>5, 8 k's
    int r  = tid >> 5;
    int k8 = (tid & 31) * 8;
    int gr = row0 + r; if (gr >= n) gr = n - 1;
    const double* Ap = A + (size_t)gr * K + k8;
    unsigned long long pack[5] = {0,0,0,0,0};
    #pragma unroll
    for (int u = 0; u < 8; ++u){
      long long v = __double2ll_rn(Ap[u] * sc);
      #pragma unroll
      for (int p = 0; p < 5; ++p){
        int d = (int)((v + 128) & 255) - 128;
        pack[p] |= (unsigned long long)(unsigned char)d << (8*u);
        v = (v - d) >> 8;
      }
    }
    #pragma unroll
    for (int p = 0; p < 5; ++p)
      *(unsigned long long*)&laq[p][r][k8] = pack[p];
  }
  __syncthreads();

  i4 acc[22];
  #pragma unroll
  for (int i = 0; i < 22; ++i){ i4 z = {0,0,0,0}; acc[i] = z; }

  const size_t NK = (size_t)N * K;
  const char* Wbase = WqT + (size_t)(ct * 16 + l15) * K + lk * 16;
  #pragma unroll
  for (int ks = 0; ks < 4; ++ks){
    int k0 = ks * 64;
    i4 af[5], bf[5];
    #pragma unroll
    for (int p = 0; p < 5; ++p)
      af[p] = *(const i4*)&laq[p][l15][k0 + lk*16];
    #pragma unroll
    for (int q = 0; q < 5; ++q)
      bf[q] = *(const i4*)(Wbase + (size_t)q * NK + k0);
    #pragma unroll
    for (int i = 0; i < 22; ++i)
      acc[i] = __builtin_amdgcn_mfma_i32_16x16x64_i8(af[PP[i]], bf[QQ[i]], acc[i], 0, 0, 0);
  }

  double s = ldexp(1.0, -(sa + sw));
  #pragma unroll
  for (int m = 0; m < 4; ++m){
    int r = row0 + lk * 4 + m;
    if (r >= n) continue;
    double sum = 0.0;
    #pragma unroll
    for (int i = 0; i < 22; ++i)
      sum += ldexp((double)acc[i][m], 8 * (PP[i] + QQ[i]));
    int c = ct * 16 + l15;
    double v = sum * s;
    if (fuse) v = gelu_d(v + (double)bias[c]);
    __builtin_nontemporal_store(v, &C[(size_t)r * N + c]);
  }
}

// ================== aggregation (unchanged) ===================================
template<typename ST, int NC>
__global__ __launch_bounds__(256)
void agg_k(const ST* __restrict__ T, const int* __restrict__ rp,
           const int* __restrict__ col, const double* __restrict__ val,
           const double* __restrict__ dinv, const float* __restrict__ bias,
           ST* __restrict__ O, int n, int fuse)
{
  constexpr int DOUT = NC * 64;
  int w = (blockIdx.x * blockDim.x + threadIdx.x) >> 6;
  int lane = threadIdx.x & 63;
  if (w >= n) return;
  double dv = dinv[w];
  const ST* Ti = T + (size_t)w * DOUT;
  double acc[NC];
  #pragma unroll
  for (int c = 0; c < NC; ++c) acc[c] = dv * (double)Ti[lane + 64*c];
  int e  = rp[w];
  int e1 = rp[w + 1];
  if (val){
    for (; e + 4 <= e1; e += 4){
      int s0 = __builtin_nontemporal_load(&col[e]);
      int s1 = __builtin_nontemporal_load(&col[e+1]);
      int s2 = __builtin_nontemporal_load(&col[e+2]);
      int s3 = __builtin_nontemporal_load(&col[e+3]);
      double v0 = __builtin_nontemporal_load(&val[e]);
      double v1 = __builtin_nontemporal_load(&val[e+1]);
      double v2 = __builtin_nontemporal_load(&val[e+2]);
      double v3 = __builtin_nontemporal_load(&val[e+3]);
      const ST* T0 = T + (size_t)s0 * DOUT;
      const ST* T1 = T + (size_t)s1 * DOUT;
      const ST* T2 = T + (size_t)s2 * DOUT;
      const ST* T3 = T + (size_t)s3 * DOUT;
      double t0[NC], t1[NC], t2[NC], t3[NC];
      #pragma unroll
      for (int c = 0; c < NC; ++c){
        t0[c] = (double)T0[lane + 64*c];
        t1[c] = (double)T1[lane + 64*c];
        t2[c] = (double)T2[lane + 64*c];
        t3[c] = (double)T3[lane + 64*c];
      }
      #pragma unroll
      for (int c = 0; c < NC; ++c){
        acc[c] = fma(v0, t0[c], acc[c]);
        acc[c] = fma(v1, t1[c], acc[c]);
        acc[c] = fma(v2, t2[c], acc[c]);
        acc[c] = fma(v3, t3[c], acc[c]);
      }
    }
    for (; e < e1; ++e){
      int s = __builtin_nontemporal_load(&col[e]);
      double v = __builtin_nontemporal_load(&val[e]);
      const ST* Ts = T + (size_t)s * DOUT;
      #pragma unroll
      for (int c = 0; c < NC; ++c) acc[c] = fma(v, (double)Ts[lane + 64*c], acc[c]);
    }
  } else {
    for (; e < e1; ++e){
      int s = col[e];
      double v = dinv[s];
      const ST* Ts = T + (size_t)s * DOUT;
      #pragma unroll
      for (int c = 0; c < NC; ++c) acc[c] = fma(v, (double)Ts[lane + 64*c], acc[c]);
    }
  }
  ST* Oi = O + (size_t)w * DOUT;
  #pragma unroll
  for (int c = 0; c < NC; ++c){
    double v = dv * acc[c];
    if (fuse) v = gelu_d(v + (double)bias[lane + 64*c]);
    __builtin_nontemporal_store((ST)v, &Oi[lane + 64*c]);
  }
}

template<typename ST>
static void run_net(const float* x, const float* t,
                    const float* W1, const float* b1, const float* W2, const float* b2,
                    const float* W3, const float* b3, const float* W4, const float* b4,
                    const float* F1, const float* c1, const float* F2, const float* c2,
                    const float* F3, const float* c3,
                    ST* b256, ST* ba, ST* bb,
                    const int* rp, const int* col, const double* val, const double* dinv,
                    char* Wq4, char* WqF2, unsigned long long* maxbuf, bool ozk,
                    float* out, int N, hipStream_t stream)
{
  auto gemm = [&](const ST* A, int K, int lda, const float* W, int NOUT, const float* bias,
                  ST* C, float* Cf, int fuse, unsigned long long* amax){
    dim3 g((N + 127) / 128, NOUT / 64);
    gemm_k<ST><<<g, dim3(BLK), 0, stream>>>(A, K, lda, W, NOUT, bias, C, Cf, N, fuse, amax);
  };
  int aggGrid = (N * 64 + BLK - 1) / BLK;
  auto agg64 = [&](const ST* T, const float* bias, ST* O, int fuse){
    agg_k<ST,1><<<dim3(aggGrid), dim3(BLK), 0, stream>>>(T, rp, col, val, dinv, bias, O, N, fuse);
  };
  auto agg128 = [&](const ST* T, const float* bias, ST* O, int fuse){
    agg_k<ST,2><<<dim3(aggGrid), dim3(BLK), 0, stream>>>(T, rp, col, val, dinv, bias, O, N, fuse);
  };

  concat_k<ST><<<dim3(1024), dim3(BLK), 0, stream>>>(x, t, ba, N);
  gemm(ba, 65, 66, W1, 64, nullptr, bb, nullptr, 0, nullptr);     // T1 -> BB
  agg64(bb, b1, ba, 1);                                           // h1 -> BA
  agg64(ba, nullptr, bb, 0);                                      // g2 -> BB
  gemm(bb, 64, 64, W2, 128, b2, ba, nullptr, 1, nullptr);         // h2 -> BA
  agg128(ba, nullptr, bb, 0);                                     // g3 -> BB
  gemm(bb, 128, 128, W3, 256, b3, b256, nullptr, 1,
       ozk ? maxbuf : nullptr);                                   // h3 -> B256, amax[0]
  if (ozk){
    if constexpr (sizeof(ST) == 8){
      ozaki_k<<<dim3((N + 15) / 16), dim3(512), 0, stream>>>(
          (const double*)b256, Wq4, maxbuf, maxbuf + 1, nullptr, (double*)ba, N, 0);
    }
  } else {
    gemm(b256, 256, 256, W4, 128, nullptr, ba, nullptr, 0, nullptr); // T4 -> BA
  }
  agg128(ba, b4, bb, 1);                                          // h4 -> BB
  gemm(bb, 128, 128, F1, 256, c1, b256, nullptr, 1,
       ozk ? maxbuf + 2 : nullptr);                               // f1 -> B256, amax[2]
  if (ozk){
    if constexpr (sizeof(ST) == 8){
      ozaki_k<<<dim3((N + 15) / 16), dim3(512), 0, stream>>>(
          (const double*)b256, WqF2, maxbuf + 2, maxbuf + 3, c2, (double*)ba, N, 1);
    }
  } else {
    gemm(b256, 256, 256, F2, 128, c2, ba, nullptr, 1, nullptr);   // f2 -> BA
  }
  gemm(ba, 128, 128, F3, 64, c3, nullptr, out, 2, nullptr);       // out
}

extern "C" void kernel_launch(void* const* d_in, const int* in_sizes, int n_in,
                              void* d_out, int out_size, void* d_ws, size_t ws_size,
                              hipStream_t stream)
{
  const float* x  = (const float*)d_in[0];
  const float* t  = (const float*)d_in[1];
  const int*   ei = (const int*)d_in[2];
  const float* W1 = (const float*)d_in[3];  const float* b1 = (const float*)d_in[4];
  const float* W2 = (const float*)d_in[5];  const float* b2 = (const float*)d_in[6];
  const float* W3 = (const float*)d_in[7];  const float* b3 = (const float*)d_in[8];
  const float* W4 = (const float*)d_in[9];  const float* b4 = (const float*)d_in[10];
  const float* F1 = (const float*)d_in[11]; const float* c1 = (const float*)d_in[12];
  const float* F2 = (const float*)d_in[13]; const float* c2 = (const float*)d_in[14];
  const float* F3 = (const float*)d_in[15]; const float* c3 = (const float*)d_in[16];
  float* out = (float*)d_out;
  int N = in_sizes[0] / 64;
  int E = in_sizes[2] / 2;

  char* p = (char*)d_ws;
  auto alloc = [&](size_t b){ char* r = p; p += (b + 255) & ~(size_t)255; return (void*)r; };
  int*    flag    = (int*)alloc(4);
  int*    cnt     = (int*)alloc((size_t)N * 4);
  int*    fill    = (int*)alloc((size_t)N * 4);
  int*    rp      = (int*)alloc((size_t)(N + 1) * 4);
  int*    partial = (int*)alloc((size_t)257 * 4);
  int*    col     = (int*)alloc((size_t)E * 4);
  double* dinv    = (double*)alloc((size_t)N * 8);
  size_t base = (size_t)(p - (char*)d_ws);

  size_t slackB = 1024;
  size_t actElems = (size_t)N * 512;
  size_t valBytes = ((size_t)E * 8 + 255) & ~(size_t)255;
  bool f64val = ws_size >= base + valBytes + actElems * sizeof(double) + 3*slackB;
  bool f64ok  = f64val || ws_size >= base + actElems * sizeof(double) + 3*slackB;
  bool f32val = ws_size >= base + valBytes + actElems * sizeof(float) + 3*slackB;
  bool f32ok  = f32val || ws_size >= base + actElems * sizeof(float) + 3*slackB;
  if (!f32ok) return;

  double* val = nullptr;
  if ((f64ok && f64val) || (!f64ok && f32val)) val = (double*)alloc((size_t)E * 8);

  int nb = 256;
  int chunk = (N + nb - 1) / nb;
  zero_k<<<dim3(256), dim3(BLK), 0, stream>>>(cnt, N);
  zero_k<<<dim3(256), dim3(BLK), 0, stream>>>(fill, N);
  detect_k<<<1, 64, 0, stream>>>(ei, flag);
  count_k<<<dim3(4096), dim3(BLK), 0, stream>>>(ei, E, flag, cnt);
  dinv_k<<<dim3((N + BLK - 1) / BLK), dim3(BLK), 0, stream>>>(cnt, dinv, N);
  scanA_k<<<dim3(nb), dim3(256), 0, stream>>>(cnt, partial, N, chunk);
  scanB_k<<<dim3(1), dim3(256), 0, stream>>>(partial, nb);
  scanC_k<<<dim3(nb), dim3(256), 0, stream>>>(cnt, partial, rp, N, chunk, nb);
  scatter_k<<<dim3(4096), dim3(BLK), 0, stream>>>(ei, E, flag, rp, fill, dinv, col, val);

  if (f64ok){
    double* b256 = (double*)alloc((size_t)N * 256 * 8 + slackB);
    double* ba   = (double*)alloc((size_t)N * 128 * 8 + slackB);
    double* bb   = (double*)alloc((size_t)N * 128 * 8 + slackB);
    // Ozaki extras: two WqT buffers (5*128*256 i8 each) + maxbuf -> ~320 KB
    size_t wqB = 5 * 128 * 256;
    size_t need = (size_t)(p - (char*)d_ws) + 2*wqB + 1024;
    bool ozk = (ws_size >= need);
    char* Wq4 = nullptr; char* WqF2 = nullptr; unsigned long long* maxbuf = nullptr;
    if (ozk){
      maxbuf = (unsigned long long*)alloc(256);
      Wq4    = (char*)alloc(wqB);
      WqF2   = (char*)alloc(wqB);
      zeromax_k<<<1, 64, 0, stream>>>(maxbuf);
      absmaxW_k<<<dim3(32), dim3(BLK), 0, stream>>>(W4, 256 * 128, maxbuf + 1);
      quantW_k<<<dim3(128), dim3(BLK), 0, stream>>>(W4, 256, 128, maxbuf + 1, Wq4);
      absmaxW_k<<<dim3(32), dim3(BLK), 0, stream>>>(F2, 256 * 128, maxbuf + 3);
      quantW_k<<<dim3(128), dim3(BLK), 0, stream>>>(F2, 256, 128, maxbuf + 3, WqF2);
    }
    run_net<double>(x, t, W1, b1, W2, b2, W3, b3, W4, b4, F1, c1, F2, c2, F3, c3,
                    b256, ba, bb, rp, col, val, dinv,
                    Wq4, WqF2, maxbuf, ozk, out, N, stream);
  } else {
    float* b256 = (float*)alloc((size_t)N * 256 * 4 + slackB);
    float* ba   = (float*)alloc((size_t)N * 128 * 4 + slackB);
    float* bb   = (float*)alloc((size_t)N * 128 * 4 + slackB);
    run_net<float>(x, t, W1, b1, W2, b2, W3, b3, W4, b4, F1, c1, F2, c2, F3, c3,
                   b256, ba, bb, rp, col, val, dinv,
                   nullptr, nullptr, nullptr, false, out, N, stream);
  }
}

// Round 12
// 2542.526 us; speedup vs baseline: 1.0070x; 1.0070x over previous
//
#include <hip/hip_runtime.h>

static constexpr int BLK = 256;

typedef double d2 __attribute__((ext_vector_type(2)));
typedef int    i4 __attribute__((ext_vector_type(4)));

__device__ __forceinline__ double gelu_d(double v){
  double u = 0.7978845608028654 * (v + 0.044715 * v * v * v);
  return 0.5 * v * (1.0 + tanh(u));
}

__global__ void zero_k(int* __restrict__ a, int n){
  int stride = gridDim.x * blockDim.x;
  for (int i = blockIdx.x*blockDim.x + threadIdx.x; i < n; i += stride) a[i] = 0;
}

__global__ void zeromax_k(unsigned long long* m){
  if (threadIdx.x == 0 && blockIdx.x == 0)
    for (int i = 0; i < 8; ++i) m[i] = 0ull;
}

// ---- edge dtype probe ----
__global__ void detect_k(const int* __restrict__ ei, int* __restrict__ flag){
  if (threadIdx.x == 0 && blockIdx.x == 0){
    int zeros = 0;
    for (int i = 0; i < 64; ++i) if (ei[2*i + 1] == 0) ++zeros;
    *flag = (zeros >= 48) ? 1 : 0;
  }
}

__global__ void count_k(const int* __restrict__ ei, int E, const int* __restrict__ flag,
                        int* __restrict__ cnt){
  int is64 = *flag;
  int stride = gridDim.x * blockDim.x;
  for (int e = blockIdx.x*blockDim.x + threadIdx.x; e < E; e += stride){
    int d = is64 ? ei[2*(E + e)] : ei[E + e];
    atomicAdd(&cnt[d], 1);
  }
}

__global__ void dinv_k(const int* __restrict__ cnt, double* __restrict__ dinv, int n){
  int i = blockIdx.x*blockDim.x + threadIdx.x;
  if (i < n){
    double deg = (double)(cnt[i] + 1);
    dinv[i] = 1.0 / sqrt(deg);
  }
}

__global__ __launch_bounds__(256)
void scanA_k(const int* __restrict__ cnt, int* __restrict__ partial, int n, int chunk){
  __shared__ int red[256];
  int b = blockIdx.x;
  int lo = b * chunk, hi = min(n, lo + chunk);
  int s = 0;
  for (int i = lo + threadIdx.x; i < hi; i += 256) s += cnt[i];
  red[threadIdx.x] = s; __syncthreads();
  for (int off = 128; off > 0; off >>= 1){
    if (threadIdx.x < off) red[threadIdx.x] += red[threadIdx.x + off];
    __syncthreads();
  }
  if (threadIdx.x == 0) partial[b] = red[0];
}

__global__ __launch_bounds__(256)
void scanB_k(int* __restrict__ partial, int nb){
  __shared__ int sd[256];
  int tid = threadIdx.x;
  int v = (tid < nb) ? partial[tid] : 0;
  sd[tid] = v; __syncthreads();
  for (int off = 1; off < 256; off <<= 1){
    int t = (tid >= off) ? sd[tid - off] : 0;
    __syncthreads();
    sd[tid] += t;
    __syncthreads();
  }
  if (tid < nb) partial[tid] = sd[tid] - v;
  if (tid == 255) partial[nb] = sd[255];
}

__global__ __launch_bounds__(256)
void scanC_k(const int* __restrict__ cnt, const int* __restrict__ partial,
             int* __restrict__ rp, int n, int chunk, int nb){
  __shared__ int sd[256];
  int b = blockIdx.x;
  int lo = b * chunk, hi = min(n, lo + chunk);
  int run = partial[b];
  for (int base = lo; base < hi; base += 256){
    int i = base + threadIdx.x;
    int v = (i < hi) ? cnt[i] : 0;
    sd[threadIdx.x] = v; __syncthreads();
    for (int off = 1; off < 256; off <<= 1){
      int t = (threadIdx.x >= off) ? sd[threadIdx.x - off] : 0;
      __syncthreads();
      sd[threadIdx.x] += t;
      __syncthreads();
    }
    if (i < hi) rp[i] = run + sd[threadIdx.x] - v;
    run += sd[255];
    __syncthreads();
  }
  if (b == 0 && threadIdx.x == 0) rp[n] = partial[nb];
}

__global__ void scatter_k(const int* __restrict__ ei, int E, const int* __restrict__ flag,
                          const int* __restrict__ rp, int* __restrict__ fill,
                          const double* __restrict__ dinv,
                          int* __restrict__ col, double* __restrict__ val){
  int is64 = *flag;
  int stride = gridDim.x * blockDim.x;
  for (int e = blockIdx.x*blockDim.x + threadIdx.x; e < E; e += stride){
    int s = is64 ? ei[2*e]       : ei[e];
    int d = is64 ? ei[2*(E + e)] : ei[E + e];
    int p = rp[d] + atomicAdd(&fill[d], 1);
    col[p] = s;
    if (val) val[p] = dinv[s];
  }
}

template<typename ST>
__global__ void concat_k(const float* __restrict__ x, const float* __restrict__ t,
                         ST* __restrict__ h0, int n){
  int total = n * 66;
  int stride = gridDim.x * blockDim.x;
  for (int idx = blockIdx.x*blockDim.x + threadIdx.x; idx < total; idx += stride){
    int row = idx / 66;
    int c = idx - row * 66;
    float v = (c < 64) ? x[row*64 + c] : (c == 64 ? t[row] : 0.0f);
    h0[idx] = (ST)v;
  }
}

// ================== f64 VALU GEMM (round-9 state) =============================
template<typename ST>
__global__ __launch_bounds__(256, 4)
void gemm_k(const ST* __restrict__ A, int K, int lda,
            const float* __restrict__ W, int NOUT,
            const float* __restrict__ bias,
            ST* __restrict__ C, float* __restrict__ Cf,
            int n, int fuse)
{
  __shared__ __align__(16) double As[128][18];
  __shared__ __align__(16) double Ws[16][66];
  const int row0 = blockIdx.x * 128;
  const int col0 = blockIdx.y * 64;
  const int tid = threadIdx.x;
  const int tr = tid >> 4, tc = tid & 15;
  const int c0 = 2 * tc;
  double acc[8][4] = {};

  const int sar = tid >> 1;
  const int sak = (tid & 1) * 8;
  const int swr = tid >> 4;
  const int swc = (tid & 15) * 4;

  const int ktiles = (K + 15) / 16;

  double ga[8];
  float  gw[4];

  auto loadA = [&](int k0){
    int gr = row0 + sar;
    if constexpr (sizeof(ST) == 8){
      if (gr < n){
        const double* Ap = (const double*)A + (size_t)gr * lda + k0 + sak;
        #pragma unroll
        for (int g = 0; g < 4; ++g){
          d2 v = *(const d2*)(Ap + 2*g);
          ga[2*g] = v.x; ga[2*g+1] = v.y;
        }
      } else {
        #pragma unroll
        for (int u = 0; u < 8; ++u) ga[u] = 0.0;
      }
    } else {
      const ST* Ap = A + (size_t)gr * lda + k0 + sak;
      #pragma unroll
      for (int u = 0; u < 8; ++u){
        int kg = k0 + sak + u;
        ga[u] = (gr < n && kg < K) ? (double)Ap[u] : 0.0;
      }
    }
  };
  auto loadW = [&](int k0){
    int kg = k0 + swr;
    if (kg < K){
      const float* Wp = W + (size_t)kg * NOUT + col0 + swc;
      #pragma unroll
      for (int g = 0; g < 4; ++g) gw[g] = Wp[g];
    } else {
      #pragma unroll
      for (int g = 0; g < 4; ++g) gw[g] = 0.0f;
    }
  };

  loadA(0);
  loadW(0);

  for (int kt = 0; kt < ktiles; ++kt){
    #pragma unroll
    for (int g = 0; g < 4; ++g){
      d2 v; v.x = ga[2*g]; v.y = ga[2*g+1];
      *(d2*)&As[sar][sak + 2*g] = v;
    }
    {
      d2 v0; v0.x = (double)gw[0]; v0.y = (double)gw[1];
      d2 v1; v1.x = (double)gw[2]; v1.y = (double)gw[3];
      *(d2*)&Ws[swr][swc]     = v0;
      *(d2*)&Ws[swr][swc + 2] = v1;
    }
    __syncthreads();
    if (kt + 1 < ktiles){
      loadA((kt + 1) * 16);
      loadW((kt + 1) * 16);
    }
    #pragma unroll
    for (int kk = 0; kk < 16; kk += 2){
      d2 w0a = *(const d2*)&Ws[kk    ][c0];
      d2 w0b = *(const d2*)&Ws[kk    ][c0 + 32];
      d2 w1a = *(const d2*)&Ws[kk + 1][c0];
      d2 w1b = *(const d2*)&Ws[kk + 1][c0 + 32];
      #pragma unroll
      for (int i = 0; i < 8; ++i){
        d2 av = *(const d2*)&As[tr + 16*i][kk];
        acc[i][0] = fma(av.x, w0a.x, acc[i][0]);
        acc[i][1] = fma(av.x, w0a.y, acc[i][1]);
        acc[i][2] = fma(av.x, w0b.x, acc[i][2]);
        acc[i][3] = fma(av.x, w0b.y, acc[i][3]);
        acc[i][0] = fma(av.y, w1a.x, acc[i][0]);
        acc[i][1] = fma(av.y, w1a.y, acc[i][1]);
        acc[i][2] = fma(av.y, w1b.x, acc[i][2]);
        acc[i][3] = fma(av.y, w1b.y, acc[i][3]);
      }
    }
    __syncthreads();
  }
  #pragma unroll
  for (int i = 0; i < 8; ++i){
    int r = row0 + tr + 16*i;
    if (r >= n) continue;
    #pragma unroll
    for (int j = 0; j < 4; ++j){
      int c = col0 + ((j < 2) ? (c0 + j) : (c0 + 30 + j));
      double v = acc[i][j];
      if (fuse){ v += (double)bias[c]; if (fuse == 1) v = gelu_d(v); }
      if (fuse == 2) __builtin_nontemporal_store((float)v, &Cf[(size_t)r * NOUT + c]);
      else           __builtin_nontemporal_store((ST)v,   &C [(size_t)r * NOUT + c]);
    }
  }
}

// ================== Ozaki int8-MFMA exact GEMM =================================
// C[n x NOUT] = A[n x K](f64) @ W[K x NOUT](f32) via 5 balanced radix-256 digit
// planes + exact i32 MFMA. sa = 37 - ilogb(am) keeps |v| < 2^38, safely inside
// the 5-digit range (+-0.996*2^39). Pairs p+q<=1 dropped (< 1e-13 relative).

__global__ void absmaxW_k(const float* __restrict__ W, int n, unsigned long long* __restrict__ out){
  double tmax = 0.0;
  int stride = gridDim.x * blockDim.x;
  for (int i = blockIdx.x*blockDim.x + threadIdx.x; i < n; i += stride)
    tmax = fmax(tmax, (double)fabsf(W[i]));
  #pragma unroll
  for (int off = 32; off > 0; off >>= 1)
    tmax = fmax(tmax, __shfl_xor(tmax, off));
  if ((threadIdx.x & 63) == 0)
    atomicMax(out, (unsigned long long)__double_as_longlong(tmax));
}

__global__ __launch_bounds__(256)
void absmaxD_k(const double* __restrict__ a, size_t L, unsigned long long* __restrict__ out){
  __shared__ double red[256];
  double tmax = 0.0;
  size_t stride = (size_t)gridDim.x * blockDim.x;
  for (size_t i = blockIdx.x*(size_t)blockDim.x + threadIdx.x; i < L; i += stride)
    tmax = fmax(tmax, fabs(a[i]));
  red[threadIdx.x] = tmax; __syncthreads();
  for (int off = 128; off > 0; off >>= 1){
    if (threadIdx.x < off) red[threadIdx.x] = fmax(red[threadIdx.x], red[threadIdx.x + off]);
    __syncthreads();
  }
  if (threadIdx.x == 0)
    atomicMax(out, (unsigned long long)__double_as_longlong(red[0]));
}

// W[K][N] f32 -> WqT[5][N][K] i8
__global__ void quantW_k(const float* __restrict__ W, int K, int N,
                         const unsigned long long* __restrict__ maxw,
                         char* __restrict__ WqT){
  double wm = __longlong_as_double((long long)*maxw);
  int sw = (wm > 0.0) ? (36 - ilogb(wm)) : 0;
  double sc = ldexp(1.0, sw);
  int total = K * N;
  size_t NK = (size_t)N * K;
  int stride = gridDim.x * blockDim.x;
  for (int t = blockIdx.x*blockDim.x + threadIdx.x; t < total; t += stride){
    int k = t / N, nn = t - k * N;
    long long v = __double2ll_rn((double)W[t] * sc);
    #pragma unroll
    for (int p = 0; p < 5; ++p){
      int d = (int)((v + 128) & 255) - 128;
      WqT[(size_t)p * NK + (size_t)nn * K + k] = (char)d;
      v = (v - d) >> 8;
    }
  }
}

// 512 thr = 8 waves; wave ct -> cols col0g + [16ct,16ct+16); block rows [16b,16b+16)
// grid: ((n+15)/16, NOUT/128). fuse: 0 raw, 1 +bias+gelu. amaxOut optional.
template<int K>
__global__ __launch_bounds__(512)
void ozaki_k(const double* __restrict__ A, const char* __restrict__ WqT,
             const unsigned long long* __restrict__ maxa,
             const unsigned long long* __restrict__ maxw,
             const float* __restrict__ bias,
             double* __restrict__ C, unsigned long long* __restrict__ amaxOut,
             int n, int NOUT, int fuse)
{
  constexpr int PAD = 16;
  constexpr int PP[22] = {0,0,0, 1,1,1,1, 2,2,2,2,2, 3,3,3,3,3, 4,4,4,4,4};
  constexpr int QQ[22] = {2,3,4, 1,2,3,4, 0,1,2,3,4, 0,1,2,3,4, 0,1,2,3,4};
  __shared__ __align__(16) char laq[5][16][K + PAD];
  __shared__ double red[8];
  const int tid  = threadIdx.x;
  const int lane = tid & 63;
  const int ct   = tid >> 6;
  const int l15  = lane & 15;
  const int lk   = lane >> 4;
  const int row0 = blockIdx.x * 16;
  const int col0g = blockIdx.y * 128;

  double am = __longlong_as_double((long long)*maxa);
  double wm = __longlong_as_double((long long)*maxw);
  int sa = (am > 0.0) ? (37 - ilogb(am)) : 0;
  int sw = (wm > 0.0) ? (36 - ilogb(wm)) : 0;
  double sc = ldexp(1.0, sa);

  { // in-kernel quantization of 16 rows x K
    int r = tid >> 5;
    int gr = row0 + r; if (gr >= n) gr = n - 1;
    if constexpr (K == 256){
      int kq = (tid & 31) * 8;
      const double* Ap = A + (size_t)gr * K + kq;
      unsigned long long pack[5] = {0,0,0,0,0};
      #pragma unroll
      for (int u = 0; u < 8; ++u){
        long long v = __double2ll_rn(Ap[u] * sc);
        #pragma unroll
        for (int p = 0; p < 5; ++p){
          int d = (int)((v + 128) & 255) - 128;
          pack[p] |= (unsigned long long)(unsigned char)d << (8*u);
          v = (v - d) >> 8;
        }
      }
      #pragma unroll
      for (int p = 0; p < 5; ++p)
        *(unsigned long long*)&laq[p][r][kq] = pack[p];
    } else {
      int kq = (tid & 31) * 4;
      const double* Ap = A + (size_t)gr * K + kq;
      unsigned int pack[5] = {0,0,0,0,0};
      #pragma unroll
      for (int u = 0; u < 4; ++u){
        long long v = __double2ll_rn(Ap[u] * sc);
        #pragma unroll
        for (int p = 0; p < 5; ++p){
          int d = (int)((v + 128) & 255) - 128;
          pack[p] |= (unsigned int)(unsigned char)d << (8*u);
          v = (v - d) >> 8;
        }
      }
      #pragma unroll
      for (int p = 0; p < 5; ++p)
        *(unsigned int*)&laq[p][r][kq] = pack[p];
    }
  }
  __syncthreads();

  i4 acc[22];
  #pragma unroll
  for (int i = 0; i < 22; ++i){ i4 z = {0,0,0,0}; acc[i] = z; }

  const size_t NK = (size_t)NOUT * K;
  const char* wb = WqT + (size_t)(col0g + ct * 16 + l15) * K + lk * 16;
  #pragma unroll
  for (int ks = 0; ks < K / 64; ++ks){
    int k0 = ks * 64;
    i4 af[5], bf[5];
    #pragma unroll
    for (int p = 0; p < 5; ++p)
      af[p] = *(const i4*)&laq[p][l15][k0 + lk*16];
    #pragma unroll
    for (int q = 0; q < 5; ++q)
      bf[q] = *(const i4*)(wb + (size_t)q * NK + k0);
    #pragma unroll
    for (int i = 0; i < 22; ++i)
      acc[i] = __builtin_amdgcn_mfma_i32_16x16x64_i8(af[PP[i]], bf[QQ[i]], acc[i], 0, 0, 0);
  }

  double s = ldexp(1.0, -(sa + sw));
  double w8[9];
  #pragma unroll
  for (int e = 2; e <= 8; ++e) w8[e] = ldexp(s, 8 * e);
  double tmax = 0.0;
  #pragma unroll
  for (int m = 0; m < 4; ++m){
    int r = row0 + lk * 4 + m;
    int c = col0g + ct * 16 + l15;
    long long g[9] = {};
    #pragma unroll
    for (int i = 0; i < 22; ++i) g[PP[i] + QQ[i]] += acc[i][m];
    double sum = 0.0;
    #pragma unroll
    for (int e = 2; e <= 8; ++e) sum = fma((double)g[e], w8[e], sum);
    double v = sum;
    if (fuse) v = gelu_d(v + (double)bias[c]);
    if (r < n){
      __builtin_nontemporal_store(v, &C[(size_t)r * NOUT + c]);
      tmax = fmax(tmax, fabs(v));
    }
  }
  if (amaxOut){
    #pragma unroll
    for (int off = 32; off > 0; off >>= 1)
      tmax = fmax(tmax, __shfl_xor(tmax, off));
    if (lane == 0) red[ct] = tmax;
    __syncthreads();
    if (tid == 0){
      double mv = red[0];
      #pragma unroll
      for (int i = 1; i < 8; ++i) mv = fmax(mv, red[i]);
      atomicMax(amaxOut, (unsigned long long)__double_as_longlong(mv));
    }
  }
}

// ================== aggregation (unchanged) ===================================
template<typename ST, int NC>
__global__ __launch_bounds__(256)
void agg_k(const ST* __restrict__ T, const int* __restrict__ rp,
           const int* __restrict__ col, const double* __restrict__ val,
           const double* __restrict__ dinv, const float* __restrict__ bias,
           ST* __restrict__ O, int n, int fuse)
{
  constexpr int DOUT = NC * 64;
  int w = (blockIdx.x * blockDim.x + threadIdx.x) >> 6;
  int lane = threadIdx.x & 63;
  if (w >= n) return;
  double dv = dinv[w];
  const ST* Ti = T + (size_t)w * DOUT;
  double acc[NC];
  #pragma unroll
  for (int c = 0; c < NC; ++c) acc[c] = dv * (double)Ti[lane + 64*c];
  int e  = rp[w];
  int e1 = rp[w + 1];
  if (val){
    for (; e + 4 <= e1; e += 4){
      int s0 = __builtin_nontemporal_load(&col[e]);
      int s1 = __builtin_nontemporal_load(&col[e+1]);
      int s2 = __builtin_nontemporal_load(&col[e+2]);
      int s3 = __builtin_nontemporal_load(&col[e+3]);
      double v0 = __builtin_nontemporal_load(&val[e]);
      double v1 = __builtin_nontemporal_load(&val[e+1]);
      double v2 = __builtin_nontemporal_load(&val[e+2]);
      double v3 = __builtin_nontemporal_load(&val[e+3]);
      const ST* T0 = T + (size_t)s0 * DOUT;
      const ST* T1 = T + (size_t)s1 * DOUT;
      const ST* T2 = T + (size_t)s2 * DOUT;
      const ST* T3 = T + (size_t)s3 * DOUT;
      double t0[NC], t1[NC], t2[NC], t3[NC];
      #pragma unroll
      for (int c = 0; c < NC; ++c){
        t0[c] = (double)T0[lane + 64*c];
        t1[c] = (double)T1[lane + 64*c];
        t2[c] = (double)T2[lane + 64*c];
        t3[c] = (double)T3[lane + 64*c];
      }
      #pragma unroll
      for (int c = 0; c < NC; ++c){
        acc[c] = fma(v0, t0[c], acc[c]);
        acc[c] = fma(v1, t1[c], acc[c]);
        acc[c] = fma(v2, t2[c], acc[c]);
        acc[c] = fma(v3, t3[c], acc[c]);
      }
    }
    for (; e < e1; ++e){
      int s = __builtin_nontemporal_load(&col[e]);
      double v = __builtin_nontemporal_load(&val[e]);
      const ST* Ts = T + (size_t)s * DOUT;
      #pragma unroll
      for (int c = 0; c < NC; ++c) acc[c] = fma(v, (double)Ts[lane + 64*c], acc[c]);
    }
  } else {
    for (; e < e1; ++e){
      int s = col[e];
      double v = dinv[s];
      const ST* Ts = T + (size_t)s * DOUT;
      #pragma unroll
      for (int c = 0; c < NC; ++c) acc[c] = fma(v, (double)Ts[lane + 64*c], acc[c]);
    }
  }
  ST* Oi = O + (size_t)w * DOUT;
  #pragma unroll
  for (int c = 0; c < NC; ++c){
    double v = dv * acc[c];
    if (fuse) v = gelu_d(v + (double)bias[lane + 64*c]);
    __builtin_nontemporal_store((ST)v, &Oi[lane + 64*c]);
  }
}

template<typename ST>
static void run_net(const float* x, const float* t,
                    const float* W1, const float* b1, const float* W2, const float* b2,
                    const float* W3, const float* b3, const float* W4, const float* b4,
                    const float* F1, const float* c1, const float* F2, const float* c2,
                    const float* F3, const float* c3,
                    ST* b256, ST* ba, ST* bb,
                    const int* rp, const int* col, const double* val, const double* dinv,
                    char* Wq3, char* Wq4, char* WqF1, char* WqF2,
                    unsigned long long* mx, bool ozk,
                    float* out, int N, hipStream_t stream)
{
  auto gemm = [&](const ST* A, int K, int lda, const float* W, int NOUT, const float* bias,
                  ST* C, float* Cf, int fuse){
    dim3 g((N + 127) / 128, NOUT / 64);
    gemm_k<ST><<<g, dim3(BLK), 0, stream>>>(A, K, lda, W, NOUT, bias, C, Cf, N, fuse);
  };
  int aggGrid = (N * 64 + BLK - 1) / BLK;
  auto agg64 = [&](const ST* T, const float* bias, ST* O, int fuse){
    agg_k<ST,1><<<dim3(aggGrid), dim3(BLK), 0, stream>>>(T, rp, col, val, dinv, bias, O, N, fuse);
  };
  auto agg128 = [&](const ST* T, const float* bias, ST* O, int fuse){
    agg_k<ST,2><<<dim3(aggGrid), dim3(BLK), 0, stream>>>(T, rp, col, val, dinv, bias, O, N, fuse);
  };

  concat_k<ST><<<dim3(1024), dim3(BLK), 0, stream>>>(x, t, ba, N);
  gemm(ba, 65, 66, W1, 64, nullptr, bb, nullptr, 0);      // T1 -> BB
  agg64(bb, b1, ba, 1);                                   // h1 -> BA
  agg64(ba, nullptr, bb, 0);                              // g2 -> BB
  gemm(bb, 64, 64, W2, 128, b2, ba, nullptr, 1);          // h2 -> BA
  agg128(ba, nullptr, bb, 0);                             // g3 -> BB
  if (ozk){
    if constexpr (sizeof(ST) == 8){
      double* dbb = (double*)bb; double* db256 = (double*)b256; double* dba = (double*)ba;
      dim3 gK128((N + 15) / 16, 2), gK256((N + 15) / 16, 1);
      absmaxD_k<<<dim3(2048), dim3(256), 0, stream>>>(dbb, (size_t)N * 128, mx + 0);
      ozaki_k<128><<<gK128, dim3(512), 0, stream>>>(dbb, Wq3, mx + 0, mx + 1, b3,
                                                    db256, mx + 2, N, 256, 1);   // h3
      ozaki_k<256><<<gK256, dim3(512), 0, stream>>>(db256, Wq4, mx + 2, mx + 3, nullptr,
                                                    dba, nullptr, N, 128, 0);    // T4
      agg128(ba, b4, bb, 1);                                                     // h4
      absmaxD_k<<<dim3(2048), dim3(256), 0, stream>>>(dbb, (size_t)N * 128, mx + 4);
      ozaki_k<128><<<gK128, dim3(512), 0, stream>>>(dbb, WqF1, mx + 4, mx + 5, c1,
                                                    db256, mx + 6, N, 256, 1);   // f1
      ozaki_k<256><<<gK256, dim3(512), 0, stream>>>(db256, WqF2, mx + 6, mx + 7, c2,
                                                    dba, nullptr, N, 128, 1);    // f2
    }
  } else {
    gemm(bb, 128, 128, W3, 256, b3, b256, nullptr, 1);    // h3 -> B256
    gemm(b256, 256, 256, W4, 128, nullptr, ba, nullptr, 0); // T4 -> BA
    agg128(ba, b4, bb, 1);                                // h4 -> BB
    gemm(bb, 128, 128, F1, 256, c1, b256, nullptr, 1);    // f1 -> B256
    gemm(b256, 256, 256, F2, 128, c2, ba, nullptr, 1);    // f2 -> BA
  }
  gemm(ba, 128, 128, F3, 64, c3, nullptr, out, 2);        // out
}

extern "C" void kernel_launch(void* const* d_in, const int* in_sizes, int n_in,
                              void* d_out, int out_size, void* d_ws, size_t ws_size,
                              hipStream_t stream)
{
  const float* x  = (const float*)d_in[0];
  const float* t  = (const float*)d_in[1];
  const int*   ei = (const int*)d_in[2];
  const float* W1 = (const float*)d_in[3];  const float* b1 = (const float*)d_in[4];
  const float* W2 = (const float*)d_in[5];  const float* b2 = (const float*)d_in[6];
  const float* W3 = (const float*)d_in[7];  const float* b3 = (const float*)d_in[8];
  const float* W4 = (const float*)d_in[9];  const float* b4 = (const float*)d_in[10];
  const float* F1 = (const float*)d_in[11]; const float* c1 = (const float*)d_in[12];
  const float* F2 = (const float*)d_in[13]; const float* c2 = (const float*)d_in[14];
  const float* F3 = (const float*)d_in[15]; const float* c3 = (const float*)d_in[16];
  float* out = (float*)d_out;
  int N = in_sizes[0] / 64;
  int E = in_sizes[2] / 2;

  char* p = (char*)d_ws;
  auto alloc = [&](size_t b){ char* r = p; p += (b + 255) & ~(size_t)255; return (void*)r; };
  int*    flag    = (int*)alloc(4);
  int*    cnt     = (int*)alloc((size_t)N * 4);
  int*    fill    = (int*)alloc((size_t)N * 4);
  int*    rp      = (int*)alloc((size_t)(N + 1) * 4);
  int*    partial = (int*)alloc((size_t)257 * 4);
  int*    col     = (int*)alloc((size_t)E * 4);
  double* dinv    = (double*)alloc((size_t)N * 8);
  size_t base = (size_t)(p - (char*)d_ws);

  size_t slackB   = 1024;
  size_t actB     = (size_t)N * 512 * sizeof(double) + 3 * slackB;
  size_t actB32   = (size_t)N * 512 * sizeof(float) + 3 * slackB;
  size_t valBytes = ((size_t)E * 8 + 255) & ~(size_t)255;
  size_t wqB      = 5 * 128 * 256;            // per matrix
  size_t wqTotal  = 256 + 4 * wqB + 8 * 256;  // maxbuf + 4 WqT + align slop

  bool ozk    = ws_size >= base + wqTotal + valBytes + actB;
  bool f64val = ozk || ws_size >= base + valBytes + actB;
  bool f64ok  = f64val || ws_size >= base + actB;
  bool f32val = ws_size >= base + valBytes + actB32;
  bool f32ok  = f32val || ws_size >= base + actB32;
  if (!f64ok && !f32ok) return;

  unsigned long long* mx = nullptr;
  char *Wq3 = nullptr, *Wq4 = nullptr, *WqF1 = nullptr, *WqF2 = nullptr;
  if (ozk){
    mx   = (unsigned long long*)alloc(256);
    Wq3  = (char*)alloc(wqB);
    Wq4  = (char*)alloc(wqB);
    WqF1 = (char*)alloc(wqB);
    WqF2 = (char*)alloc(wqB);
  }

  double* val = nullptr;
  if (f64ok ? f64val : f32val) val = (double*)alloc((size_t)E * 8);

  int nb = 256;
  int chunk = (N + nb - 1) / nb;
  zero_k<<<dim3(256), dim3(BLK), 0, stream>>>(cnt, N);
  zero_k<<<dim3(256), dim3(BLK), 0, stream>>>(fill, N);
  detect_k<<<1, 64, 0, stream>>>(ei, flag);
  count_k<<<dim3(4096), dim3(BLK), 0, stream>>>(ei, E, flag, cnt);
  dinv_k<<<dim3((N + BLK - 1) / BLK), dim3(BLK), 0, stream>>>(cnt, dinv, N);
  scanA_k<<<dim3(nb), dim3(256), 0, stream>>>(cnt, partial, N, chunk);
  scanB_k<<<dim3(1), dim3(256), 0, stream>>>(partial, nb);
  scanC_k<<<dim3(nb), dim3(256), 0, stream>>>(cnt, partial, rp, N, chunk, nb);
  scatter_k<<<dim3(4096), dim3(BLK), 0, stream>>>(ei, E, flag, rp, fill, dinv, col, val);

  if (ozk){
    zeromax_k<<<1, 64, 0, stream>>>(mx);
    absmaxW_k<<<dim3(32), dim3(BLK), 0, stream>>>(W3, 128 * 256, mx + 1);
    quantW_k<<<dim3(128), dim3(BLK), 0, stream>>>(W3, 128, 256, mx + 1, Wq3);
    absmaxW_k<<<dim3(32), dim3(BLK), 0, stream>>>(W4, 256 * 128, mx + 3);
    quantW_k<<<dim3(128), dim3(BLK), 0, stream>>>(W4, 256, 128, mx + 3, Wq4);
    absmaxW_k<<<dim3(32), dim3(BLK), 0, stream>>>(F1, 128 * 256, mx + 5);
    quantW_k<<<dim3(128), dim3(BLK), 0, stream>>>(F1, 128, 256, mx + 5, WqF1);
    absmaxW_k<<<dim3(32), dim3(BLK), 0, stream>>>(F2, 256 * 128, mx + 7);
    quantW_k<<<dim3(128), dim3(BLK), 0, stream>>>(F2, 256, 128, mx + 7, WqF2);
  }

  if (f64ok){
    double* b256 = (double*)alloc((size_t)N * 256 * 8 + slackB);
    double* ba   = (double*)alloc((size_t)N * 128 * 8 + slackB);
    double* bb   = (double*)alloc((size_t)N * 128 * 8 + slackB);
    run_net<double>(x, t, W1, b1, W2, b2, W3, b3, W4, b4, F1, c1, F2, c2, F3, c3,
                    b256, ba, bb, rp, col, val, dinv,
                    Wq3, Wq4, WqF1, WqF2, mx, ozk, out, N, stream);
  } else {
    float* b256 = (float*)alloc((size_t)N * 256 * 4 + slackB);
    float* ba   = (float*)alloc((size_t)N * 128 * 4 + slackB);
    float* bb   = (float*)alloc((size_t)N * 128 * 4 + slackB);
    run_net<float>(x, t, W1, b1, W2, b2, W3, b3, W4, b4, F1, c1, F2, c2, F3, c3,
                   b256, ba, bb, rp, col, val, dinv,
                   nullptr, nullptr, nullptr, nullptr, nullptr, false, out, N, stream);
  }
}

// Round 13
// 2538.982 us; speedup vs baseline: 1.0084x; 1.0014x over previous
//
#include <hip/hip_runtime.h>

static constexpr int BLK = 256;

typedef double d2 __attribute__((ext_vector_type(2)));
typedef int    i4 __attribute__((ext_vector_type(4)));

__device__ __forceinline__ double gelu_d(double v){
  double u = 0.7978845608028654 * (v + 0.044715 * v * v * v);
  return 0.5 * v * (1.0 + tanh(u));
}

__global__ void zero_k(int* __restrict__ a, int n){
  int stride = gridDim.x * blockDim.x;
  for (int i = blockIdx.x*blockDim.x + threadIdx.x; i < n; i += stride) a[i] = 0;
}

__global__ void zeromax_k(unsigned long long* m){
  if (threadIdx.x == 0 && blockIdx.x == 0)
    for (int i = 0; i < 8; ++i) m[i] = 0ull;
}

// ---- edge dtype probe ----
__global__ void detect_k(const int* __restrict__ ei, int* __restrict__ flag){
  if (threadIdx.x == 0 && blockIdx.x == 0){
    int zeros = 0;
    for (int i = 0; i < 64; ++i) if (ei[2*i + 1] == 0) ++zeros;
    *flag = (zeros >= 48) ? 1 : 0;
  }
}

__global__ void count_k(const int* __restrict__ ei, int E, const int* __restrict__ flag,
                        int* __restrict__ cnt){
  int is64 = *flag;
  int stride = gridDim.x * blockDim.x;
  for (int e = blockIdx.x*blockDim.x + threadIdx.x; e < E; e += stride){
    int d = is64 ? ei[2*(E + e)] : ei[E + e];
    atomicAdd(&cnt[d], 1);
  }
}

__global__ void dinv_k(const int* __restrict__ cnt, double* __restrict__ dinv, int n){
  int i = blockIdx.x*blockDim.x + threadIdx.x;
  if (i < n){
    double deg = (double)(cnt[i] + 1);
    dinv[i] = 1.0 / sqrt(deg);
  }
}

__global__ __launch_bounds__(256)
void scanA_k(const int* __restrict__ cnt, int* __restrict__ partial, int n, int chunk){
  __shared__ int red[256];
  int b = blockIdx.x;
  int lo = b * chunk, hi = min(n, lo + chunk);
  int s = 0;
  for (int i = lo + threadIdx.x; i < hi; i += 256) s += cnt[i];
  red[threadIdx.x] = s; __syncthreads();
  for (int off = 128; off > 0; off >>= 1){
    if (threadIdx.x < off) red[threadIdx.x] += red[threadIdx.x + off];
    __syncthreads();
  }
  if (threadIdx.x == 0) partial[b] = red[0];
}

__global__ __launch_bounds__(256)
void scanB_k(int* __restrict__ partial, int nb){
  __shared__ int sd[256];
  int tid = threadIdx.x;
  int v = (tid < nb) ? partial[tid] : 0;
  sd[tid] = v; __syncthreads();
  for (int off = 1; off < 256; off <<= 1){
    int t = (tid >= off) ? sd[tid - off] : 0;
    __syncthreads();
    sd[tid] += t;
    __syncthreads();
  }
  if (tid < nb) partial[tid] = sd[tid] - v;
  if (tid == 255) partial[nb] = sd[255];
}

__global__ __launch_bounds__(256)
void scanC_k(const int* __restrict__ cnt, const int* __restrict__ partial,
             int* __restrict__ rp, int n, int chunk, int nb){
  __shared__ int sd[256];
  int b = blockIdx.x;
  int lo = b * chunk, hi = min(n, lo + chunk);
  int run = partial[b];
  for (int base = lo; base < hi; base += 256){
    int i = base + threadIdx.x;
    int v = (i < hi) ? cnt[i] : 0;
    sd[threadIdx.x] = v; __syncthreads();
    for (int off = 1; off < 256; off <<= 1){
      int t = (threadIdx.x >= off) ? sd[threadIdx.x - off] : 0;
      __syncthreads();
      sd[threadIdx.x] += t;
      __syncthreads();
    }
    if (i < hi) rp[i] = run + sd[threadIdx.x] - v;
    run += sd[255];
    __syncthreads();
  }
  if (b == 0 && threadIdx.x == 0) rp[n] = partial[nb];
}

__global__ void scatter_k(const int* __restrict__ ei, int E, const int* __restrict__ flag,
                          const int* __restrict__ rp, int* __restrict__ fill,
                          const double* __restrict__ dinv,
                          int* __restrict__ col, double* __restrict__ val){
  int is64 = *flag;
  int stride = gridDim.x * blockDim.x;
  for (int e = blockIdx.x*blockDim.x + threadIdx.x; e < E; e += stride){
    int s = is64 ? ei[2*e]       : ei[e];
    int d = is64 ? ei[2*(E + e)] : ei[E + e];
    int p = rp[d] + atomicAdd(&fill[d], 1);
    col[p] = s;
    if (val) val[p] = dinv[s];
  }
}

template<typename ST>
__global__ void concat_k(const float* __restrict__ x, const float* __restrict__ t,
                         ST* __restrict__ h0, int n){
  int total = n * 66;
  int stride = gridDim.x * blockDim.x;
  for (int idx = blockIdx.x*blockDim.x + threadIdx.x; idx < total; idx += stride){
    int row = idx / 66;
    int c = idx - row * 66;
    float v = (c < 64) ? x[row*64 + c] : (c == 64 ? t[row] : 0.0f);
    h0[idx] = (ST)v;
  }
}

// ================== f64 VALU GEMM (round-9 state) =============================
template<typename ST>
__global__ __launch_bounds__(256, 4)
void gemm_k(const ST* __restrict__ A, int K, int lda,
            const float* __restrict__ W, int NOUT,
            const float* __restrict__ bias,
            ST* __restrict__ C, float* __restrict__ Cf,
            int n, int fuse)
{
  __shared__ __align__(16) double As[128][18];
  __shared__ __align__(16) double Ws[16][66];
  const int row0 = blockIdx.x * 128;
  const int col0 = blockIdx.y * 64;
  const int tid = threadIdx.x;
  const int tr = tid >> 4, tc = tid & 15;
  const int c0 = 2 * tc;
  double acc[8][4] = {};

  const int sar = tid >> 1;
  const int sak = (tid & 1) * 8;
  const int swr = tid >> 4;
  const int swc = (tid & 15) * 4;

  const int ktiles = (K + 15) / 16;

  double ga[8];
  float  gw[4];

  auto loadA = [&](int k0){
    int gr = row0 + sar;
    if constexpr (sizeof(ST) == 8){
      if (gr < n){
        const double* Ap = (const double*)A + (size_t)gr * lda + k0 + sak;
        #pragma unroll
        for (int g = 0; g < 4; ++g){
          d2 v = *(const d2*)(Ap + 2*g);
          ga[2*g] = v.x; ga[2*g+1] = v.y;
        }
      } else {
        #pragma unroll
        for (int u = 0; u < 8; ++u) ga[u] = 0.0;
      }
    } else {
      const ST* Ap = A + (size_t)gr * lda + k0 + sak;
      #pragma unroll
      for (int u = 0; u < 8; ++u){
        int kg = k0 + sak + u;
        ga[u] = (gr < n && kg < K) ? (double)Ap[u] : 0.0;
      }
    }
  };
  auto loadW = [&](int k0){
    int kg = k0 + swr;
    if (kg < K){
      const float* Wp = W + (size_t)kg * NOUT + col0 + swc;
      #pragma unroll
      for (int g = 0; g < 4; ++g) gw[g] = Wp[g];
    } else {
      #pragma unroll
      for (int g = 0; g < 4; ++g) gw[g] = 0.0f;
    }
  };

  loadA(0);
  loadW(0);

  for (int kt = 0; kt < ktiles; ++kt){
    #pragma unroll
    for (int g = 0; g < 4; ++g){
      d2 v; v.x = ga[2*g]; v.y = ga[2*g+1];
      *(d2*)&As[sar][sak + 2*g] = v;
    }
    {
      d2 v0; v0.x = (double)gw[0]; v0.y = (double)gw[1];
      d2 v1; v1.x = (double)gw[2]; v1.y = (double)gw[3];
      *(d2*)&Ws[swr][swc]     = v0;
      *(d2*)&Ws[swr][swc + 2] = v1;
    }
    __syncthreads();
    if (kt + 1 < ktiles){
      loadA((kt + 1) * 16);
      loadW((kt + 1) * 16);
    }
    #pragma unroll
    for (int kk = 0; kk < 16; kk += 2){
      d2 w0a = *(const d2*)&Ws[kk    ][c0];
      d2 w0b = *(const d2*)&Ws[kk    ][c0 + 32];
      d2 w1a = *(const d2*)&Ws[kk + 1][c0];
      d2 w1b = *(const d2*)&Ws[kk + 1][c0 + 32];
      #pragma unroll
      for (int i = 0; i < 8; ++i){
        d2 av = *(const d2*)&As[tr + 16*i][kk];
        acc[i][0] = fma(av.x, w0a.x, acc[i][0]);
        acc[i][1] = fma(av.x, w0a.y, acc[i][1]);
        acc[i][2] = fma(av.x, w0b.x, acc[i][2]);
        acc[i][3] = fma(av.x, w0b.y, acc[i][3]);
        acc[i][0] = fma(av.y, w1a.x, acc[i][0]);
        acc[i][1] = fma(av.y, w1a.y, acc[i][1]);
        acc[i][2] = fma(av.y, w1b.x, acc[i][2]);
        acc[i][3] = fma(av.y, w1b.y, acc[i][3]);
      }
    }
    __syncthreads();
  }
  #pragma unroll
  for (int i = 0; i < 8; ++i){
    int r = row0 + tr + 16*i;
    if (r >= n) continue;
    #pragma unroll
    for (int j = 0; j < 4; ++j){
      int c = col0 + ((j < 2) ? (c0 + j) : (c0 + 30 + j));
      double v = acc[i][j];
      if (fuse){ v += (double)bias[c]; if (fuse == 1) v = gelu_d(v); }
      if (fuse == 2) __builtin_nontemporal_store((float)v, &Cf[(size_t)r * NOUT + c]);
      else           __builtin_nontemporal_store((ST)v,   &C [(size_t)r * NOUT + c]);
    }
  }
}

// ================== Ozaki int8-MFMA exact GEMM =================================
// C[n x NOUT] = A[n x K](f64) @ W[K x NOUT](f32) via 5 balanced radix-256 digit
// planes + exact i32 MFMA. sa = 37 - ilogb(am) keeps |v| < 2^38, inside the
// 5-digit range. Pairs p+q<=1 dropped (< 1e-12 relative).

__global__ void absmaxW_k(const float* __restrict__ W, int n, unsigned long long* __restrict__ out){
  double tmax = 0.0;
  int stride = gridDim.x * blockDim.x;
  for (int i = blockIdx.x*blockDim.x + threadIdx.x; i < n; i += stride)
    tmax = fmax(tmax, (double)fabsf(W[i]));
  #pragma unroll
  for (int off = 32; off > 0; off >>= 1)
    tmax = fmax(tmax, __shfl_xor(tmax, off));
  if ((threadIdx.x & 63) == 0)
    atomicMax(out, (unsigned long long)__double_as_longlong(tmax));
}

__global__ __launch_bounds__(256)
void absmaxD_k(const double* __restrict__ a, size_t L, unsigned long long* __restrict__ out){
  __shared__ double red[256];
  double tmax = 0.0;
  size_t stride = (size_t)gridDim.x * blockDim.x;
  for (size_t i = blockIdx.x*(size_t)blockDim.x + threadIdx.x; i < L; i += stride)
    tmax = fmax(tmax, fabs(a[i]));
  red[threadIdx.x] = tmax; __syncthreads();
  for (int off = 128; off > 0; off >>= 1){
    if (threadIdx.x < off) red[threadIdx.x] = fmax(red[threadIdx.x], red[threadIdx.x + off]);
    __syncthreads();
  }
  if (threadIdx.x == 0)
    atomicMax(out, (unsigned long long)__double_as_longlong(red[0]));
}

// W[K][N] f32 -> WqT[5][N][K] i8
__global__ void quantW_k(const float* __restrict__ W, int K, int N,
                         const unsigned long long* __restrict__ maxw,
                         char* __restrict__ WqT){
  double wm = __longlong_as_double((long long)*maxw);
  int sw = (wm > 0.0) ? (36 - ilogb(wm)) : 0;
  double sc = ldexp(1.0, sw);
  int total = K * N;
  size_t NK = (size_t)N * K;
  int stride = gridDim.x * blockDim.x;
  for (int t = blockIdx.x*blockDim.x + threadIdx.x; t < total; t += stride){
    int k = t / N, nn = t - k * N;
    long long v = __double2ll_rn((double)W[t] * sc);
    #pragma unroll
    for (int p = 0; p < 5; ++p){
      int d = (int)((v + 128) & 255) - 128;
      WqT[(size_t)p * NK + (size_t)nn * K + k] = (char)d;
      v = (v - d) >> 8;
    }
  }
}

// 512 thr = 8 waves; wave ct -> cols col0g + [16ct,16ct+16); block rows [16b,16b+16)
// grid: ((n+15)/16, NOUT/128). fuse: 0 raw, 1 +bias+gelu. amaxOut optional.
template<int K>
__global__ __launch_bounds__(512)
void ozaki_k(const double* __restrict__ A, const char* __restrict__ WqT,
             const unsigned long long* __restrict__ maxa,
             const unsigned long long* __restrict__ maxw,
             const float* __restrict__ bias,
             double* __restrict__ C, unsigned long long* __restrict__ amaxOut,
             int n, int NOUT, int fuse)
{
  constexpr int PAD = 16;
  constexpr int PP[22] = {0,0,0, 1,1,1,1, 2,2,2,2,2, 3,3,3,3,3, 4,4,4,4,4};
  constexpr int QQ[22] = {2,3,4, 1,2,3,4, 0,1,2,3,4, 0,1,2,3,4, 0,1,2,3,4};
  __shared__ __align__(16) char laq[5][16][K + PAD];
  __shared__ double red[8];
  const int tid  = threadIdx.x;
  const int lane = tid & 63;
  const int ct   = tid >> 6;
  const int l15  = lane & 15;
  const int lk   = lane >> 4;
  const int row0 = blockIdx.x * 16;
  const int col0g = blockIdx.y * 128;

  double am = __longlong_as_double((long long)*maxa);
  double wm = __longlong_as_double((long long)*maxw);
  int sa = (am > 0.0) ? (37 - ilogb(am)) : 0;
  int sw = (wm > 0.0) ? (36 - ilogb(wm)) : 0;
  double sc = ldexp(1.0, sa);

  { // in-kernel quantization of 16 rows x K
    int r = tid >> 5;
    int gr = row0 + r; if (gr >= n) gr = n - 1;
    if constexpr (K == 256){
      int kq = (tid & 31) * 8;
      const double* Ap = A + (size_t)gr * K + kq;
      unsigned long long pack[5] = {0,0,0,0,0};
      #pragma unroll
      for (int u = 0; u < 8; ++u){
        long long v = __double2ll_rn(Ap[u] * sc);
        #pragma unroll
        for (int p = 0; p < 5; ++p){
          int d = (int)((v + 128) & 255) - 128;
          pack[p] |= (unsigned long long)(unsigned char)d << (8*u);
          v = (v - d) >> 8;
        }
      }
      #pragma unroll
      for (int p = 0; p < 5; ++p)
        *(unsigned long long*)&laq[p][r][kq] = pack[p];
    } else {
      int kq = (tid & 31) * 4;
      const double* Ap = A + (size_t)gr * K + kq;
      unsigned int pack[5] = {0,0,0,0,0};
      #pragma unroll
      for (int u = 0; u < 4; ++u){
        long long v = __double2ll_rn(Ap[u] * sc);
        #pragma unroll
        for (int p = 0; p < 5; ++p){
          int d = (int)((v + 128) & 255) - 128;
          pack[p] |= (unsigned int)(unsigned char)d << (8*u);
          v = (v - d) >> 8;
        }
      }
      #pragma unroll
      for (int p = 0; p < 5; ++p)
        *(unsigned int*)&laq[p][r][kq] = pack[p];
    }
  }
  __syncthreads();

  i4 acc[22];
  #pragma unroll
  for (int i = 0; i < 22; ++i){ i4 z = {0,0,0,0}; acc[i] = z; }

  const size_t NK = (size_t)NOUT * K;
  const char* wb = WqT + (size_t)(col0g + ct * 16 + l15) * K + lk * 16;
  #pragma unroll
  for (int ks = 0; ks < K / 64; ++ks){
    int k0 = ks * 64;
    i4 af[5], bf[5];
    #pragma unroll
    for (int p = 0; p < 5; ++p)
      af[p] = *(const i4*)&laq[p][l15][k0 + lk*16];
    #pragma unroll
    for (int q = 0; q < 5; ++q)
      bf[q] = *(const i4*)(wb + (size_t)q * NK + k0);
    #pragma unroll
    for (int i = 0; i < 22; ++i)
      acc[i] = __builtin_amdgcn_mfma_i32_16x16x64_i8(af[PP[i]], bf[QQ[i]], acc[i], 0, 0, 0);
  }

  double s = ldexp(1.0, -(sa + sw));
  double w8[9];
  #pragma unroll
  for (int e = 2; e <= 8; ++e) w8[e] = ldexp(s, 8 * e);
  double tmax = 0.0;
  #pragma unroll
  for (int m = 0; m < 4; ++m){
    int r = row0 + lk * 4 + m;
    int c = col0g + ct * 16 + l15;
    long long g[9] = {};
    #pragma unroll
    for (int i = 0; i < 22; ++i) g[PP[i] + QQ[i]] += acc[i][m];
    double sum = 0.0;
    #pragma unroll
    for (int e = 2; e <= 8; ++e) sum = fma((double)g[e], w8[e], sum);
    double v = sum;
    if (fuse) v = gelu_d(v + (double)bias[c]);
    if (r < n){
      __builtin_nontemporal_store(v, &C[(size_t)r * NOUT + c]);
      tmax = fmax(tmax, fabs(v));
    }
  }
  if (amaxOut){
    #pragma unroll
    for (int off = 32; off > 0; off >>= 1)
      tmax = fmax(tmax, __shfl_xor(tmax, off));
    if (lane == 0) red[ct] = tmax;
    __syncthreads();
    if (tid == 0){
      double mv = red[0];
      #pragma unroll
      for (int i = 1; i < 8; ++i) mv = fmax(mv, red[i]);
      atomicMax(amaxOut, (unsigned long long)__double_as_longlong(mv));
    }
  }
}

// ================== aggregation (no-val path now unrolled x4) =================
template<typename ST, int NC>
__global__ __launch_bounds__(256)
void agg_k(const ST* __restrict__ T, const int* __restrict__ rp,
           const int* __restrict__ col, const double* __restrict__ val,
           const double* __restrict__ dinv, const float* __restrict__ bias,
           ST* __restrict__ O, int n, int fuse)
{
  constexpr int DOUT = NC * 64;
  int w = (blockIdx.x * blockDim.x + threadIdx.x) >> 6;
  int lane = threadIdx.x & 63;
  if (w >= n) return;
  double dv = dinv[w];
  const ST* Ti = T + (size_t)w * DOUT;
  double acc[NC];
  #pragma unroll
  for (int c = 0; c < NC; ++c) acc[c] = dv * (double)Ti[lane + 64*c];
  int e  = rp[w];
  int e1 = rp[w + 1];
  if (val){
    for (; e + 4 <= e1; e += 4){
      int s0 = __builtin_nontemporal_load(&col[e]);
      int s1 = __builtin_nontemporal_load(&col[e+1]);
      int s2 = __builtin_nontemporal_load(&col[e+2]);
      int s3 = __builtin_nontemporal_load(&col[e+3]);
      double v0 = __builtin_nontemporal_load(&val[e]);
      double v1 = __builtin_nontemporal_load(&val[e+1]);
      double v2 = __builtin_nontemporal_load(&val[e+2]);
      double v3 = __builtin_nontemporal_load(&val[e+3]);
      const ST* T0 = T + (size_t)s0 * DOUT;
      const ST* T1 = T + (size_t)s1 * DOUT;
      const ST* T2 = T + (size_t)s2 * DOUT;
      const ST* T3 = T + (size_t)s3 * DOUT;
      double t0[NC], t1[NC], t2[NC], t3[NC];
      #pragma unroll
      for (int c = 0; c < NC; ++c){
        t0[c] = (double)T0[lane + 64*c];
        t1[c] = (double)T1[lane + 64*c];
        t2[c] = (double)T2[lane + 64*c];
        t3[c] = (double)T3[lane + 64*c];
      }
      #pragma unroll
      for (int c = 0; c < NC; ++c){
        acc[c] = fma(v0, t0[c], acc[c]);
        acc[c] = fma(v1, t1[c], acc[c]);
        acc[c] = fma(v2, t2[c], acc[c]);
        acc[c] = fma(v3, t3[c], acc[c]);
      }
    }
    for (; e < e1; ++e){
      int s = __builtin_nontemporal_load(&col[e]);
      double v = __builtin_nontemporal_load(&val[e]);
      const ST* Ts = T + (size_t)s * DOUT;
      #pragma unroll
      for (int c = 0; c < NC; ++c) acc[c] = fma(v, (double)Ts[lane + 64*c], acc[c]);
    }
  } else {
    for (; e + 4 <= e1; e += 4){
      int s0 = __builtin_nontemporal_load(&col[e]);
      int s1 = __builtin_nontemporal_load(&col[e+1]);
      int s2 = __builtin_nontemporal_load(&col[e+2]);
      int s3 = __builtin_nontemporal_load(&col[e+3]);
      double v0 = dinv[s0];
      double v1 = dinv[s1];
      double v2 = dinv[s2];
      double v3 = dinv[s3];
      const ST* T0 = T + (size_t)s0 * DOUT;
      const ST* T1 = T + (size_t)s1 * DOUT;
      const ST* T2 = T + (size_t)s2 * DOUT;
      const ST* T3 = T + (size_t)s3 * DOUT;
      double t0[NC], t1[NC], t2[NC], t3[NC];
      #pragma unroll
      for (int c = 0; c < NC; ++c){
        t0[c] = (double)T0[lane + 64*c];
        t1[c] = (double)T1[lane + 64*c];
        t2[c] = (double)T2[lane + 64*c];
        t3[c] = (double)T3[lane + 64*c];
      }
      #pragma unroll
      for (int c = 0; c < NC; ++c){
        acc[c] = fma(v0, t0[c], acc[c]);
        acc[c] = fma(v1, t1[c], acc[c]);
        acc[c] = fma(v2, t2[c], acc[c]);
        acc[c] = fma(v3, t3[c], acc[c]);
      }
    }
    for (; e < e1; ++e){
      int s = __builtin_nontemporal_load(&col[e]);
      double v = dinv[s];
      const ST* Ts = T + (size_t)s * DOUT;
      #pragma unroll
      for (int c = 0; c < NC; ++c) acc[c] = fma(v, (double)Ts[lane + 64*c], acc[c]);
    }
  }
  ST* Oi = O + (size_t)w * DOUT;
  #pragma unroll
  for (int c = 0; c < NC; ++c){
    double v = dv * acc[c];
    if (fuse) v = gelu_d(v + (double)bias[lane + 64*c]);
    __builtin_nontemporal_store((ST)v, &Oi[lane + 64*c]);
  }
}

template<typename ST>
static void run_net(const float* x, const float* t,
                    const float* W1, const float* b1, const float* W2, const float* b2,
                    const float* W3, const float* b3, const float* W4, const float* b4,
                    const float* F1, const float* c1, const float* F2, const float* c2,
                    const float* F3, const float* c3,
                    ST* b256, ST* ba, ST* bb,
                    const int* rp, const int* col, const double* val, const double* dinv,
                    char* Wq3, char* Wq4, char* WqF1, char* WqF2,
                    unsigned long long* mx, bool ozk,
                    float* out, int N, hipStream_t stream)
{
  auto gemm = [&](const ST* A, int K, int lda, const float* W, int NOUT, const float* bias,
                  ST* C, float* Cf, int fuse){
    dim3 g((N + 127) / 128, NOUT / 64);
    gemm_k<ST><<<g, dim3(BLK), 0, stream>>>(A, K, lda, W, NOUT, bias, C, Cf, N, fuse);
  };
  int aggGrid = (N * 64 + BLK - 1) / BLK;
  auto agg64 = [&](const ST* T, const float* bias, ST* O, int fuse){
    agg_k<ST,1><<<dim3(aggGrid), dim3(BLK), 0, stream>>>(T, rp, col, val, dinv, bias, O, N, fuse);
  };
  auto agg128 = [&](const ST* T, const float* bias, ST* O, int fuse){
    agg_k<ST,2><<<dim3(aggGrid), dim3(BLK), 0, stream>>>(T, rp, col, val, dinv, bias, O, N, fuse);
  };

  concat_k<ST><<<dim3(1024), dim3(BLK), 0, stream>>>(x, t, ba, N);
  gemm(ba, 65, 66, W1, 64, nullptr, bb, nullptr, 0);      // T1 -> BB
  agg64(bb, b1, ba, 1);                                   // h1 -> BA
  agg64(ba, nullptr, bb, 0);                              // g2 -> BB
  gemm(bb, 64, 64, W2, 128, b2, ba, nullptr, 1);          // h2 -> BA
  agg128(ba, nullptr, bb, 0);                             // g3 -> BB
  if (ozk){
    if constexpr (sizeof(ST) == 8){
      double* dbb = (double*)bb; double* db256 = (double*)b256; double* dba = (double*)ba;
      dim3 gK128((N + 15) / 16, 2), gK256((N + 15) / 16, 1);
      absmaxD_k<<<dim3(2048), dim3(256), 0, stream>>>(dbb, (size_t)N * 128, mx + 0);
      ozaki_k<128><<<gK128, dim3(512), 0, stream>>>(dbb, Wq3, mx + 0, mx + 1, b3,
                                                    db256, mx + 2, N, 256, 1);   // h3
      ozaki_k<256><<<gK256, dim3(512), 0, stream>>>(db256, Wq4, mx + 2, mx + 3, nullptr,
                                                    dba, nullptr, N, 128, 0);    // T4
      agg128(ba, b4, bb, 1);                                                     // h4
      absmaxD_k<<<dim3(2048), dim3(256), 0, stream>>>(dbb, (size_t)N * 128, mx + 4);
      ozaki_k<128><<<gK128, dim3(512), 0, stream>>>(dbb, WqF1, mx + 4, mx + 5, c1,
                                                    db256, mx + 6, N, 256, 1);   // f1
      ozaki_k<256><<<gK256, dim3(512), 0, stream>>>(db256, WqF2, mx + 6, mx + 7, c2,
                                                    dba, nullptr, N, 128, 1);    // f2
    }
  } else {
    gemm(bb, 128, 128, W3, 256, b3, b256, nullptr, 1);    // h3 -> B256
    gemm(b256, 256, 256, W4, 128, nullptr, ba, nullptr, 0); // T4 -> BA
    agg128(ba, b4, bb, 1);                                // h4 -> BB
    gemm(bb, 128, 128, F1, 256, c1, b256, nullptr, 1);    // f1 -> B256
    gemm(b256, 256, 256, F2, 128, c2, ba, nullptr, 1);    // f2 -> BA
  }
  gemm(ba, 128, 128, F3, 64, c3, nullptr, out, 2);        // out
}

extern "C" void kernel_launch(void* const* d_in, const int* in_sizes, int n_in,
                              void* d_out, int out_size, void* d_ws, size_t ws_size,
                              hipStream_t stream)
{
  const float* x  = (const float*)d_in[0];
  const float* t  = (const float*)d_in[1];
  const int*   ei = (const int*)d_in[2];
  const float* W1 = (const float*)d_in[3];  const float* b1 = (const float*)d_in[4];
  const float* W2 = (const float*)d_in[5];  const float* b2 = (const float*)d_in[6];
  const float* W3 = (const float*)d_in[7];  const float* b3 = (const float*)d_in[8];
  const float* W4 = (const float*)d_in[9];  const float* b4 = (const float*)d_in[10];
  const float* F1 = (const float*)d_in[11]; const float* c1 = (const float*)d_in[12];
  const float* F2 = (const float*)d_in[13]; const float* c2 = (const float*)d_in[14];
  const float* F3 = (const float*)d_in[15]; const float* c3 = (const float*)d_in[16];
  float* out = (float*)d_out;
  int N = in_sizes[0] / 64;
  int E = in_sizes[2] / 2;

  char* p = (char*)d_ws;
  auto alloc = [&](size_t b){ char* r = p; p += (b + 255) & ~(size_t)255; return (void*)r; };
  int*    flag    = (int*)alloc(4);
  int*    cnt     = (int*)alloc((size_t)N * 4);
  int*    fill    = (int*)alloc((size_t)N * 4);
  int*    rp      = (int*)alloc((size_t)(N + 1) * 4);
  int*    partial = (int*)alloc((size_t)257 * 4);
  int*    col     = (int*)alloc((size_t)E * 4);
  double* dinv    = (double*)alloc((size_t)N * 8);
  size_t base = (size_t)(p - (char*)d_ws);

  size_t slackB   = 1024;
  size_t actB     = (size_t)N * 512 * 8 + 3 * slackB;
  size_t actB32   = (size_t)N * 512 * 4 + 3 * slackB;
  size_t valB     = ((size_t)E * 8 + 255) & ~(size_t)255;
  size_t wqB      = 5 * 128 * 256;
  size_t wqTot    = 256 + 4 * wqB;     // mx + 4 WqT (all 256-aligned)

  bool f64base = ws_size >= base + actB;
  bool ozk     = f64base && (ws_size >= base + wqTot + actB);
  bool f32base = ws_size >= base + actB32;
  if (!f64base && !f32base) return;

  // PRIORITY: Wq buffers (0.66 MB, unlock MFMA path) BEFORE val (25.6 MB).
  unsigned long long* mx = nullptr;
  char *Wq3 = nullptr, *Wq4 = nullptr, *WqF1 = nullptr, *WqF2 = nullptr;
  if (ozk){
    mx   = (unsigned long long*)alloc(256);
    Wq3  = (char*)alloc(wqB);
    Wq4  = (char*)alloc(wqB);
    WqF1 = (char*)alloc(wqB);
    WqF2 = (char*)alloc(wqB);
  }

  int nb = 256;
  int chunk = (N + nb - 1) / nb;

  if (f64base){
    double* b256 = (double*)alloc((size_t)N * 256 * 8 + slackB);
    double* ba   = (double*)alloc((size_t)N * 128 * 8 + slackB);
    double* bb   = (double*)alloc((size_t)N * 128 * 8 + slackB);
    double* val  = nullptr;
    if (ws_size >= (size_t)(p - (char*)d_ws) + valB)
      val = (double*)alloc((size_t)E * 8);

    zero_k<<<dim3(256), dim3(BLK), 0, stream>>>(cnt, N);
    zero_k<<<dim3(256), dim3(BLK), 0, stream>>>(fill, N);
    detect_k<<<1, 64, 0, stream>>>(ei, flag);
    count_k<<<dim3(4096), dim3(BLK), 0, stream>>>(ei, E, flag, cnt);
    dinv_k<<<dim3((N + BLK - 1) / BLK), dim3(BLK), 0, stream>>>(cnt, dinv, N);
    scanA_k<<<dim3(nb), dim3(256), 0, stream>>>(cnt, partial, N, chunk);
    scanB_k<<<dim3(1), dim3(256), 0, stream>>>(partial, nb);
    scanC_k<<<dim3(nb), dim3(256), 0, stream>>>(cnt, partial, rp, N, chunk, nb);
    scatter_k<<<dim3(4096), dim3(BLK), 0, stream>>>(ei, E, flag, rp, fill, dinv, col, val);

    if (ozk){
      zeromax_k<<<1, 64, 0, stream>>>(mx);
      absmaxW_k<<<dim3(32), dim3(BLK), 0, stream>>>(W3, 128 * 256, mx + 1);
      quantW_k<<<dim3(128), dim3(BLK), 0, stream>>>(W3, 128, 256, mx + 1, Wq3);
      absmaxW_k<<<dim3(32), dim3(BLK), 0, stream>>>(W4, 256 * 128, mx + 3);
      quantW_k<<<dim3(128), dim3(BLK), 0, stream>>>(W4, 256, 128, mx + 3, Wq4);
      absmaxW_k<<<dim3(32), dim3(BLK), 0, stream>>>(F1, 128 * 256, mx + 5);
      quantW_k<<<dim3(128), dim3(BLK), 0, stream>>>(F1, 128, 256, mx + 5, WqF1);
      absmaxW_k<<<dim3(32), dim3(BLK), 0, stream>>>(F2, 256 * 128, mx + 7);
      quantW_k<<<dim3(128), dim3(BLK), 0, stream>>>(F2, 256, 128, mx + 7, WqF2);
    }
    run_net<double>(x, t, W1, b1, W2, b2, W3, b3, W4, b4, F1, c1, F2, c2, F3, c3,
                    b256, ba, bb, rp, col, val, dinv,
                    Wq3, Wq4, WqF1, WqF2, mx, ozk, out, N, stream);
  } else {
    float* b256 = (float*)alloc((size_t)N * 256 * 4 + slackB);
    float* ba   = (float*)alloc((size_t)N * 128 * 4 + slackB);
    float* bb   = (float*)alloc((size_t)N * 128 * 4 + slackB);
    double* val = nullptr;
    if (ws_size >= (size_t)(p - (char*)d_ws) + valB)
      val = (double*)alloc((size_t)E * 8);

    zero_k<<<dim3(256), dim3(BLK), 0, stream>>>(cnt, N);
    zero_k<<<dim3(256), dim3(BLK), 0, stream>>>(fill, N);
    detect_k<<<1, 64, 0, stream>>>(ei, flag);
    count_k<<<dim3(4096), dim3(BLK), 0, stream>>>(ei, E, flag, cnt);
    dinv_k<<<dim3((N + BLK - 1) / BLK), dim3(BLK), 0, stream>>>(cnt, dinv, N);
    scanA_k<<<dim3(nb), dim3(256), 0, stream>>>(cnt, partial, N, chunk);
    scanB_k<<<dim3(1), dim3(256), 0, stream>>>(partial, nb);
    scanC_k<<<dim3(nb), dim3(256), 0, stream>>>(cnt, partial, rp, N, chunk, nb);
    scatter_k<<<dim3(4096), dim3(BLK), 0, stream>>>(ei, E, flag, rp, fill, dinv, col, val);

    run_net<float>(x, t, W1, b1, W2, b2, W3, b3, W4, b4, F1, c1, F2, c2, F3, c3,
                   b256, ba, bb, rp, col, val, dinv,
                   nullptr, nullptr, nullptr, nullptr, nullptr, false, out, N, stream);
  }
}

// Round 14
// 2531.924 us; speedup vs baseline: 1.0113x; 1.0028x over previous
//
#include <hip/hip_runtime.h>

static constexpr int BLK = 256;

typedef double d2 __attribute__((ext_vector_type(2)));
typedef int    i4 __attribute__((ext_vector_type(4)));

__device__ __forceinline__ double gelu_d(double v){
  double u = 0.7978845608028654 * (v + 0.044715 * v * v * v);
  return 0.5 * v * (1.0 + tanh(u));
}

__global__ void zero_k(int* __restrict__ a, int n){
  int stride = gridDim.x * blockDim.x;
  for (int i = blockIdx.x*blockDim.x + threadIdx.x; i < n; i += stride) a[i] = 0;
}

__global__ void zeromax_k(unsigned long long* m){
  if (threadIdx.x == 0 && blockIdx.x == 0)
    for (int i = 0; i < 8; ++i) m[i] = 0ull;
}

// ---- edge dtype probe ----
__global__ void detect_k(const int* __restrict__ ei, int* __restrict__ flag){
  if (threadIdx.x == 0 && blockIdx.x == 0){
    int zeros = 0;
    for (int i = 0; i < 64; ++i) if (ei[2*i + 1] == 0) ++zeros;
    *flag = (zeros >= 48) ? 1 : 0;
  }
}

__global__ void count_k(const int* __restrict__ ei, int E, const int* __restrict__ flag,
                        int* __restrict__ cnt){
  int is64 = *flag;
  int stride = gridDim.x * blockDim.x;
  for (int e = blockIdx.x*blockDim.x + threadIdx.x; e < E; e += stride){
    int d = is64 ? ei[2*(E + e)] : ei[E + e];
    atomicAdd(&cnt[d], 1);
  }
}

__global__ void dinv_k(const int* __restrict__ cnt, double* __restrict__ dinv, int n){
  int i = blockIdx.x*blockDim.x + threadIdx.x;
  if (i < n){
    double deg = (double)(cnt[i] + 1);
    dinv[i] = 1.0 / sqrt(deg);
  }
}

__global__ __launch_bounds__(256)
void scanA_k(const int* __restrict__ cnt, int* __restrict__ partial, int n, int chunk){
  __shared__ int red[256];
  int b = blockIdx.x;
  int lo = b * chunk, hi = min(n, lo + chunk);
  int s = 0;
  for (int i = lo + threadIdx.x; i < hi; i += 256) s += cnt[i];
  red[threadIdx.x] = s; __syncthreads();
  for (int off = 128; off > 0; off >>= 1){
    if (threadIdx.x < off) red[threadIdx.x] += red[threadIdx.x + off];
    __syncthreads();
  }
  if (threadIdx.x == 0) partial[b] = red[0];
}

__global__ __launch_bounds__(256)
void scanB_k(int* __restrict__ partial, int nb){
  __shared__ int sd[256];
  int tid = threadIdx.x;
  int v = (tid < nb) ? partial[tid] : 0;
  sd[tid] = v; __syncthreads();
  for (int off = 1; off < 256; off <<= 1){
    int t = (tid >= off) ? sd[tid - off] : 0;
    __syncthreads();
    sd[tid] += t;
    __syncthreads();
  }
  if (tid < nb) partial[tid] = sd[tid] - v;
  if (tid == 255) partial[nb] = sd[255];
}

__global__ __launch_bounds__(256)
void scanC_k(const int* __restrict__ cnt, const int* __restrict__ partial,
             int* __restrict__ rp, int n, int chunk, int nb){
  __shared__ int sd[256];
  int b = blockIdx.x;
  int lo = b * chunk, hi = min(n, lo + chunk);
  int run = partial[b];
  for (int base = lo; base < hi; base += 256){
    int i = base + threadIdx.x;
    int v = (i < hi) ? cnt[i] : 0;
    sd[threadIdx.x] = v; __syncthreads();
    for (int off = 1; off < 256; off <<= 1){
      int t = (threadIdx.x >= off) ? sd[threadIdx.x - off] : 0;
      __syncthreads();
      sd[threadIdx.x] += t;
      __syncthreads();
    }
    if (i < hi) rp[i] = run + sd[threadIdx.x] - v;
    run += sd[255];
    __syncthreads();
  }
  if (b == 0 && threadIdx.x == 0) rp[n] = partial[nb];
}

__global__ void scatter_k(const int* __restrict__ ei, int E, const int* __restrict__ flag,
                          const int* __restrict__ rp, int* __restrict__ fill,
                          int* __restrict__ col){
  int is64 = *flag;
  int stride = gridDim.x * blockDim.x;
  for (int e = blockIdx.x*blockDim.x + threadIdx.x; e < E; e += stride){
    int s = is64 ? ei[2*e]       : ei[e];
    int d = is64 ? ei[2*(E + e)] : ei[E + e];
    int p = rp[d] + atomicAdd(&fill[d], 1);
    col[p] = s;
  }
}

template<typename ST>
__global__ void concat_k(const float* __restrict__ x, const float* __restrict__ t,
                         ST* __restrict__ h0, int n){
  int total = n * 66;
  int stride = gridDim.x * blockDim.x;
  for (int idx = blockIdx.x*blockDim.x + threadIdx.x; idx < total; idx += stride){
    int row = idx / 66;
    int c = idx - row * 66;
    float v = (c < 64) ? x[row*64 + c] : (c == 64 ? t[row] : 0.0f);
    h0[idx] = (ST)v;
  }
}

// ================== f64 VALU GEMM (round-9 state) =============================
template<typename ST>
__global__ __launch_bounds__(256, 4)
void gemm_k(const ST* __restrict__ A, int K, int lda,
            const float* __restrict__ W, int NOUT,
            const float* __restrict__ bias,
            ST* __restrict__ C, float* __restrict__ Cf,
            int n, int fuse)
{
  __shared__ __align__(16) double As[128][18];
  __shared__ __align__(16) double Ws[16][66];
  const int row0 = blockIdx.x * 128;
  const int col0 = blockIdx.y * 64;
  const int tid = threadIdx.x;
  const int tr = tid >> 4, tc = tid & 15;
  const int c0 = 2 * tc;
  double acc[8][4] = {};

  const int sar = tid >> 1;
  const int sak = (tid & 1) * 8;
  const int swr = tid >> 4;
  const int swc = (tid & 15) * 4;

  const int ktiles = (K + 15) / 16;

  double ga[8];
  float  gw[4];

  auto loadA = [&](int k0){
    int gr = row0 + sar;
    if constexpr (sizeof(ST) == 8){
      if (gr < n){
        const double* Ap = (const double*)A + (size_t)gr * lda + k0 + sak;
        #pragma unroll
        for (int g = 0; g < 4; ++g){
          d2 v = *(const d2*)(Ap + 2*g);
          ga[2*g] = v.x; ga[2*g+1] = v.y;
        }
      } else {
        #pragma unroll
        for (int u = 0; u < 8; ++u) ga[u] = 0.0;
      }
    } else {
      const ST* Ap = A + (size_t)gr * lda + k0 + sak;
      #pragma unroll
      for (int u = 0; u < 8; ++u){
        int kg = k0 + sak + u;
        ga[u] = (gr < n && kg < K) ? (double)Ap[u] : 0.0;
      }
    }
  };
  auto loadW = [&](int k0){
    int kg = k0 + swr;
    if (kg < K){
      const float* Wp = W + (size_t)kg * NOUT + col0 + swc;
      #pragma unroll
      for (int g = 0; g < 4; ++g) gw[g] = Wp[g];
    } else {
      #pragma unroll
      for (int g = 0; g < 4; ++g) gw[g] = 0.0f;
    }
  };

  loadA(0);
  loadW(0);

  for (int kt = 0; kt < ktiles; ++kt){
    #pragma unroll
    for (int g = 0; g < 4; ++g){
      d2 v; v.x = ga[2*g]; v.y = ga[2*g+1];
      *(d2*)&As[sar][sak + 2*g] = v;
    }
    {
      d2 v0; v0.x = (double)gw[0]; v0.y = (double)gw[1];
      d2 v1; v1.x = (double)gw[2]; v1.y = (double)gw[3];
      *(d2*)&Ws[swr][swc]     = v0;
      *(d2*)&Ws[swr][swc + 2] = v1;
    }
    __syncthreads();
    if (kt + 1 < ktiles){
      loadA((kt + 1) * 16);
      loadW((kt + 1) * 16);
    }
    #pragma unroll
    for (int kk = 0; kk < 16; kk += 2){
      d2 w0a = *(const d2*)&Ws[kk    ][c0];
      d2 w0b = *(const d2*)&Ws[kk    ][c0 + 32];
      d2 w1a = *(const d2*)&Ws[kk + 1][c0];
      d2 w1b = *(const d2*)&Ws[kk + 1][c0 + 32];
      #pragma unroll
      for (int i = 0; i < 8; ++i){
        d2 av = *(const d2*)&As[tr + 16*i][kk];
        acc[i][0] = fma(av.x, w0a.x, acc[i][0]);
        acc[i][1] = fma(av.x, w0a.y, acc[i][1]);
        acc[i][2] = fma(av.x, w0b.x, acc[i][2]);
        acc[i][3] = fma(av.x, w0b.y, acc[i][3]);
        acc[i][0] = fma(av.y, w1a.x, acc[i][0]);
        acc[i][1] = fma(av.y, w1a.y, acc[i][1]);
        acc[i][2] = fma(av.y, w1b.x, acc[i][2]);
        acc[i][3] = fma(av.y, w1b.y, acc[i][3]);
      }
    }
    __syncthreads();
  }
  #pragma unroll
  for (int i = 0; i < 8; ++i){
    int r = row0 + tr + 16*i;
    if (r >= n) continue;
    #pragma unroll
    for (int j = 0; j < 4; ++j){
      int c = col0 + ((j < 2) ? (c0 + j) : (c0 + 30 + j));
      double v = acc[i][j];
      if (fuse){ v += (double)bias[c]; if (fuse == 1) v = gelu_d(v); }
      if (fuse == 2) __builtin_nontemporal_store((float)v, &Cf[(size_t)r * NOUT + c]);
      else           __builtin_nontemporal_store((ST)v,   &C [(size_t)r * NOUT + c]);
    }
  }
}

// ================== Ozaki int8-MFMA exact GEMM =================================
// C[n x NOUT] = A[n x K](f64) @ W[K x NOUT](f32) via 5 balanced radix-256 digit
// planes + exact i32 MFMA. sa = 37 - ilogb(am) keeps |v| < 2^38, inside the
// 5-digit range. Pairs p+q<=1 dropped (< 1e-12 relative).
// Wq buffer + mx live in the DEAD prologue buffers (cnt/fill) -> zero extra ws.

__global__ void absmaxW_k(const float* __restrict__ W, int n, unsigned long long* __restrict__ out){
  double tmax = 0.0;
  int stride = gridDim.x * blockDim.x;
  for (int i = blockIdx.x*blockDim.x + threadIdx.x; i < n; i += stride)
    tmax = fmax(tmax, (double)fabsf(W[i]));
  #pragma unroll
  for (int off = 32; off > 0; off >>= 1)
    tmax = fmax(tmax, __shfl_xor(tmax, off));
  if ((threadIdx.x & 63) == 0)
    atomicMax(out, (unsigned long long)__double_as_longlong(tmax));
}

__global__ __launch_bounds__(256)
void absmaxD_k(const double* __restrict__ a, size_t L, unsigned long long* __restrict__ out){
  __shared__ double red[256];
  double tmax = 0.0;
  size_t stride = (size_t)gridDim.x * blockDim.x;
  for (size_t i = blockIdx.x*(size_t)blockDim.x + threadIdx.x; i < L; i += stride)
    tmax = fmax(tmax, fabs(a[i]));
  red[threadIdx.x] = tmax; __syncthreads();
  for (int off = 128; off > 0; off >>= 1){
    if (threadIdx.x < off) red[threadIdx.x] = fmax(red[threadIdx.x], red[threadIdx.x + off]);
    __syncthreads();
  }
  if (threadIdx.x == 0)
    atomicMax(out, (unsigned long long)__double_as_longlong(red[0]));
}

// W[K][N] f32 -> WqT[5][N][K] i8
__global__ void quantW_k(const float* __restrict__ W, int K, int N,
                         const unsigned long long* __restrict__ maxw,
                         char* __restrict__ WqT){
  double wm = __longlong_as_double((long long)*maxw);
  int sw = (wm > 0.0) ? (36 - ilogb(wm)) : 0;
  double sc = ldexp(1.0, sw);
  int total = K * N;
  size_t NK = (size_t)N * K;
  int stride = gridDim.x * blockDim.x;
  for (int t = blockIdx.x*blockDim.x + threadIdx.x; t < total; t += stride){
    int k = t / N, nn = t - k * N;
    long long v = __double2ll_rn((double)W[t] * sc);
    #pragma unroll
    for (int p = 0; p < 5; ++p){
      int d = (int)((v + 128) & 255) - 128;
      WqT[(size_t)p * NK + (size_t)nn * K + k] = (char)d;
      v = (v - d) >> 8;
    }
  }
}

// 512 thr = 8 waves; wave ct -> cols col0g + [16ct,16ct+16); block rows [16b,16b+16)
// grid: ((n+15)/16, NOUT/128). fuse: 0 raw, 1 +bias+gelu. amaxOut optional.
template<int K>
__global__ __launch_bounds__(512)
void ozaki_k(const double* __restrict__ A, const char* __restrict__ WqT,
             const unsigned long long* __restrict__ maxa,
             const unsigned long long* __restrict__ maxw,
             const float* __restrict__ bias,
             double* __restrict__ C, unsigned long long* __restrict__ amaxOut,
             int n, int NOUT, int fuse)
{
  constexpr int PAD = 16;
  constexpr int PP[22] = {0,0,0, 1,1,1,1, 2,2,2,2,2, 3,3,3,3,3, 4,4,4,4,4};
  constexpr int QQ[22] = {2,3,4, 1,2,3,4, 0,1,2,3,4, 0,1,2,3,4, 0,1,2,3,4};
  __shared__ __align__(16) char laq[5][16][K + PAD];
  __shared__ double red[8];
  const int tid  = threadIdx.x;
  const int lane = tid & 63;
  const int ct   = tid >> 6;
  const int l15  = lane & 15;
  const int lk   = lane >> 4;
  const int row0 = blockIdx.x * 16;
  const int col0g = blockIdx.y * 128;

  double am = __longlong_as_double((long long)*maxa);
  double wm = __longlong_as_double((long long)*maxw);
  int sa = (am > 0.0) ? (37 - ilogb(am)) : 0;
  int sw = (wm > 0.0) ? (36 - ilogb(wm)) : 0;
  double sc = ldexp(1.0, sa);

  { // in-kernel quantization of 16 rows x K
    int r = tid >> 5;
    int gr = row0 + r; if (gr >= n) gr = n - 1;
    if constexpr (K == 256){
      int kq = (tid & 31) * 8;
      const double* Ap = A + (size_t)gr * K + kq;
      unsigned long long pack[5] = {0,0,0,0,0};
      #pragma unroll
      for (int u = 0; u < 8; ++u){
        long long v = __double2ll_rn(Ap[u] * sc);
        #pragma unroll
        for (int p = 0; p < 5; ++p){
          int d = (int)((v + 128) & 255) - 128;
          pack[p] |= (unsigned long long)(unsigned char)d << (8*u);
          v = (v - d) >> 8;
        }
      }
      #pragma unroll
      for (int p = 0; p < 5; ++p)
        *(unsigned long long*)&laq[p][r][kq] = pack[p];
    } else {
      int kq = (tid & 31) * 4;
      const double* Ap = A + (size_t)gr * K + kq;
      unsigned int pack[5] = {0,0,0,0,0};
      #pragma unroll
      for (int u = 0; u < 4; ++u){
        long long v = __double2ll_rn(Ap[u] * sc);
        #pragma unroll
        for (int p = 0; p < 5; ++p){
          int d = (int)((v + 128) & 255) - 128;
          pack[p] |= (unsigned int)(unsigned char)d << (8*u);
          v = (v - d) >> 8;
        }
      }
      #pragma unroll
      for (int p = 0; p < 5; ++p)
        *(unsigned int*)&laq[p][r][kq] = pack[p];
    }
  }
  __syncthreads();

  i4 acc[22];
  #pragma unroll
  for (int i = 0; i < 22; ++i){ i4 z = {0,0,0,0}; acc[i] = z; }

  const size_t NK = (size_t)NOUT * K;
  const char* wb = WqT + (size_t)(col0g + ct * 16 + l15) * K + lk * 16;
  #pragma unroll
  for (int ks = 0; ks < K / 64; ++ks){
    int k0 = ks * 64;
    i4 af[5], bf[5];
    #pragma unroll
    for (int p = 0; p < 5; ++p)
      af[p] = *(const i4*)&laq[p][l15][k0 + lk*16];
    #pragma unroll
    for (int q = 0; q < 5; ++q)
      bf[q] = *(const i4*)(wb + (size_t)q * NK + k0);
    #pragma unroll
    for (int i = 0; i < 22; ++i)
      acc[i] = __builtin_amdgcn_mfma_i32_16x16x64_i8(af[PP[i]], bf[QQ[i]], acc[i], 0, 0, 0);
  }

  double s = ldexp(1.0, -(sa + sw));
  double w8[9];
  #pragma unroll
  for (int e = 2; e <= 8; ++e) w8[e] = ldexp(s, 8 * e);
  double tmax = 0.0;
  #pragma unroll
  for (int m = 0; m < 4; ++m){
    int r = row0 + lk * 4 + m;
    int c = col0g + ct * 16 + l15;
    long long g[9] = {};
    #pragma unroll
    for (int i = 0; i < 22; ++i) g[PP[i] + QQ[i]] += acc[i][m];
    double sum = 0.0;
    #pragma unroll
    for (int e = 2; e <= 8; ++e) sum = fma((double)g[e], w8[e], sum);
    double v = sum;
    if (fuse) v = gelu_d(v + (double)bias[c]);
    if (r < n){
      __builtin_nontemporal_store(v, &C[(size_t)r * NOUT + c]);
      tmax = fmax(tmax, fabs(v));
    }
  }
  if (amaxOut){
    #pragma unroll
    for (int off = 32; off > 0; off >>= 1)
      tmax = fmax(tmax, __shfl_xor(tmax, off));
    if (lane == 0) red[ct] = tmax;
    __syncthreads();
    if (tid == 0){
      double mv = red[0];
      #pragma unroll
      for (int i = 1; i < 8; ++i) mv = fmax(mv, red[i]);
      atomicMax(amaxOut, (unsigned long long)__double_as_longlong(mv));
    }
  }
}

// ================== aggregation (dinv-gather, unrolled x4) ====================
template<typename ST, int NC>
__global__ __launch_bounds__(256)
void agg_k(const ST* __restrict__ T, const int* __restrict__ rp,
           const int* __restrict__ col, const double* __restrict__ dinv,
           const float* __restrict__ bias, ST* __restrict__ O, int n, int fuse)
{
  constexpr int DOUT = NC * 64;
  int w = (blockIdx.x * blockDim.x + threadIdx.x) >> 6;
  int lane = threadIdx.x & 63;
  if (w >= n) return;
  double dv = dinv[w];
  const ST* Ti = T + (size_t)w * DOUT;
  double acc[NC];
  #pragma unroll
  for (int c = 0; c < NC; ++c) acc[c] = dv * (double)Ti[lane + 64*c];
  int e  = rp[w];
  int e1 = rp[w + 1];
  for (; e + 4 <= e1; e += 4){
    int s0 = __builtin_nontemporal_load(&col[e]);
    int s1 = __builtin_nontemporal_load(&col[e+1]);
    int s2 = __builtin_nontemporal_load(&col[e+2]);
    int s3 = __builtin_nontemporal_load(&col[e+3]);
    double v0 = dinv[s0];
    double v1 = dinv[s1];
    double v2 = dinv[s2];
    double v3 = dinv[s3];
    const ST* T0 = T + (size_t)s0 * DOUT;
    const ST* T1 = T + (size_t)s1 * DOUT;
    const ST* T2 = T + (size_t)s2 * DOUT;
    const ST* T3 = T + (size_t)s3 * DOUT;
    double t0[NC], t1[NC], t2[NC], t3[NC];
    #pragma unroll
    for (int c = 0; c < NC; ++c){
      t0[c] = (double)T0[lane + 64*c];
      t1[c] = (double)T1[lane + 64*c];
      t2[c] = (double)T2[lane + 64*c];
      t3[c] = (double)T3[lane + 64*c];
    }
    #pragma unroll
    for (int c = 0; c < NC; ++c){
      acc[c] = fma(v0, t0[c], acc[c]);
      acc[c] = fma(v1, t1[c], acc[c]);
      acc[c] = fma(v2, t2[c], acc[c]);
      acc[c] = fma(v3, t3[c], acc[c]);
    }
  }
  for (; e < e1; ++e){
    int s = __builtin_nontemporal_load(&col[e]);
    double v = dinv[s];
    const ST* Ts = T + (size_t)s * DOUT;
    #pragma unroll
    for (int c = 0; c < NC; ++c) acc[c] = fma(v, (double)Ts[lane + 64*c], acc[c]);
  }
  ST* Oi = O + (size_t)w * DOUT;
  #pragma unroll
  for (int c = 0; c < NC; ++c){
    double v = dv * acc[c];
    if (fuse) v = gelu_d(v + (double)bias[lane + 64*c]);
    __builtin_nontemporal_store((ST)v, &Oi[lane + 64*c]);
  }
}

template<typename ST>
static void run_net(const float* x, const float* t,
                    const float* W1, const float* b1, const float* W2, const float* b2,
                    const float* W3, const float* b3, const float* W4, const float* b4,
                    const float* F1, const float* c1, const float* F2, const float* c2,
                    const float* F3, const float* c3,
                    ST* b256, ST* ba, ST* bb,
                    const int* rp, const int* col, const double* dinv,
                    char* Wq, unsigned long long* mx, bool ozk,
                    float* out, int N, hipStream_t stream)
{
  auto gemm = [&](const ST* A, int K, int lda, const float* W, int NOUT, const float* bias,
                  ST* C, float* Cf, int fuse){
    dim3 g((N + 127) / 128, NOUT / 64);
    gemm_k<ST><<<g, dim3(BLK), 0, stream>>>(A, K, lda, W, NOUT, bias, C, Cf, N, fuse);
  };
  int aggGrid = (N * 64 + BLK - 1) / BLK;
  auto agg64 = [&](const ST* T, const float* bias, ST* O, int fuse){
    agg_k<ST,1><<<dim3(aggGrid), dim3(BLK), 0, stream>>>(T, rp, col, dinv, bias, O, N, fuse);
  };
  auto agg128 = [&](const ST* T, const float* bias, ST* O, int fuse){
    agg_k<ST,2><<<dim3(aggGrid), dim3(BLK), 0, stream>>>(T, rp, col, dinv, bias, O, N, fuse);
  };

  concat_k<ST><<<dim3(1024), dim3(BLK), 0, stream>>>(x, t, ba, N);
  gemm(ba, 65, 66, W1, 64, nullptr, bb, nullptr, 0);      // T1 -> BB
  agg64(bb, b1, ba, 1);                                   // h1 -> BA
  agg64(ba, nullptr, bb, 0);                              // g2 -> BB
  gemm(bb, 64, 64, W2, 128, b2, ba, nullptr, 1);          // h2 -> BA
  agg128(ba, nullptr, bb, 0);                             // g3 -> BB
  if (ozk){
    if constexpr (sizeof(ST) == 8){
      double* dbb = (double*)bb; double* db256 = (double*)b256; double* dba = (double*)ba;
      dim3 gK128((N + 15) / 16, 2), gK256((N + 15) / 16, 1);
      zeromax_k<<<1, 64, 0, stream>>>(mx);
      absmaxD_k<<<dim3(2048), dim3(256), 0, stream>>>(dbb, (size_t)N * 128, mx + 0);
      absmaxW_k<<<dim3(32), dim3(BLK), 0, stream>>>(W3, 128 * 256, mx + 1);
      quantW_k<<<dim3(128), dim3(BLK), 0, stream>>>(W3, 128, 256, mx + 1, Wq);
      ozaki_k<128><<<gK128, dim3(512), 0, stream>>>(dbb, Wq, mx + 0, mx + 1, b3,
                                                    db256, mx + 2, N, 256, 1);   // h3
      absmaxW_k<<<dim3(32), dim3(BLK), 0, stream>>>(W4, 256 * 128, mx + 3);
      quantW_k<<<dim3(128), dim3(BLK), 0, stream>>>(W4, 256, 128, mx + 3, Wq);
      ozaki_k<256><<<gK256, dim3(512), 0, stream>>>(db256, Wq, mx + 2, mx + 3, nullptr,
                                                    dba, nullptr, N, 128, 0);    // T4
      agg128(ba, b4, bb, 1);                                                     // h4
      absmaxD_k<<<dim3(2048), dim3(256), 0, stream>>>(dbb, (size_t)N * 128, mx + 4);
      absmaxW_k<<<dim3(32), dim3(BLK), 0, stream>>>(F1, 128 * 256, mx + 5);
      quantW_k<<<dim3(128), dim3(BLK), 0, stream>>>(F1, 128, 256, mx + 5, Wq);
      ozaki_k<128><<<gK128, dim3(512), 0, stream>>>(dbb, Wq, mx + 4, mx + 5, c1,
                                                    db256, mx + 6, N, 256, 1);   // f1
      absmaxW_k<<<dim3(32), dim3(BLK), 0, stream>>>(F2, 256 * 128, mx + 7);
      quantW_k<<<dim3(128), dim3(BLK), 0, stream>>>(F2, 256, 128, mx + 7, Wq);
      ozaki_k<256><<<gK256, dim3(512), 0, stream>>>(db256, Wq, mx + 6, mx + 7, c2,
                                                    dba, nullptr, N, 128, 1);    // f2
    }
  } else {
    gemm(bb, 128, 128, W3, 256, b3, b256, nullptr, 1);    // h3 -> B256
    gemm(b256, 256, 256, W4, 128, nullptr, ba, nullptr, 0); // T4 -> BA
    agg128(ba, b4, bb, 1);                                // h4 -> BB
    gemm(bb, 128, 128, F1, 256, c1, b256, nullptr, 1);    // f1 -> B256
    gemm(b256, 256, 256, F2, 128, c2, ba, nullptr, 1);    // f2 -> BA
  }
  gemm(ba, 128, 128, F3, 64, c3, nullptr, out, 2);        // out
}

extern "C" void kernel_launch(void* const* d_in, const int* in_sizes, int n_in,
                              void* d_out, int out_size, void* d_ws, size_t ws_size,
                              hipStream_t stream)
{
  const float* x  = (const float*)d_in[0];
  const float* t  = (const float*)d_in[1];
  const int*   ei = (const int*)d_in[2];
  const float* W1 = (const float*)d_in[3];  const float* b1 = (const float*)d_in[4];
  const float* W2 = (const float*)d_in[5];  const float* b2 = (const float*)d_in[6];
  const float* W3 = (const float*)d_in[7];  const float* b3 = (const float*)d_in[8];
  const float* W4 = (const float*)d_in[9];  const float* b4 = (const float*)d_in[10];
  const float* F1 = (const float*)d_in[11]; const float* c1 = (const float*)d_in[12];
  const float* F2 = (const float*)d_in[13]; const float* c2 = (const float*)d_in[14];
  const float* F3 = (const float*)d_in[15]; const float* c3 = (const float*)d_in[16];
  float* out = (float*)d_out;
  int N = in_sizes[0] / 64;
  int E = in_sizes[2] / 2;

  char* p = (char*)d_ws;
  auto alloc = [&](size_t b){ char* r = p; p += (b + 255) & ~(size_t)255; return (void*)r; };
  int*    flag    = (int*)alloc(4);
  int*    cnt     = (int*)alloc((size_t)N * 4);   // reused as Wq after scatter
  int*    fill    = (int*)alloc((size_t)N * 4);   // reused as mx after scatter
  int*    rp      = (int*)alloc((size_t)(N + 1) * 4);
  int*    partial = (int*)alloc((size_t)257 * 4);
  int*    col     = (int*)alloc((size_t)E * 4);
  double* dinv    = (double*)alloc((size_t)N * 8);
  size_t base = (size_t)(p - (char*)d_ws);

  size_t slackB = 1024;
  size_t actB   = (size_t)N * 512 * 8 + 3 * slackB;
  size_t actB32 = (size_t)N * 512 * 4 + 3 * slackB;

  bool f64base = ws_size >= base + actB;
  bool f32base = ws_size >= base + actB32;
  if (!f64base && !f32base) return;

  int nb = 256;
  int chunk = (N + nb - 1) / nb;

  zero_k<<<dim3(256), dim3(BLK), 0, stream>>>(cnt, N);
  zero_k<<<dim3(256), dim3(BLK), 0, stream>>>(fill, N);
  detect_k<<<1, 64, 0, stream>>>(ei, flag);
  count_k<<<dim3(4096), dim3(BLK), 0, stream>>>(ei, E, flag, cnt);
  dinv_k<<<dim3((N + BLK - 1) / BLK), dim3(BLK), 0, stream>>>(cnt, dinv, N);
  scanA_k<<<dim3(nb), dim3(256), 0, stream>>>(cnt, partial, N, chunk);
  scanB_k<<<dim3(1), dim3(256), 0, stream>>>(partial, nb);
  scanC_k<<<dim3(nb), dim3(256), 0, stream>>>(cnt, partial, rp, N, chunk, nb);
  scatter_k<<<dim3(4096), dim3(BLK), 0, stream>>>(ei, E, flag, rp, fill, col);
  // cnt & fill are DEAD from here on; reuse as Wq (160 KB) and mx (64 B).
  char* Wq = (char*)cnt;
  unsigned long long* mx = (unsigned long long*)fill;

  if (f64base){
    double* b256 = (double*)alloc((size_t)N * 256 * 8 + slackB);
    double* ba   = (double*)alloc((size_t)N * 128 * 8 + slackB);
    double* bb   = (double*)alloc((size_t)N * 128 * 8 + slackB);
    run_net<double>(x, t, W1, b1, W2, b2, W3, b3, W4, b4, F1, c1, F2, c2, F3, c3,
                    b256, ba, bb, rp, col, dinv,
                    Wq, mx, true, out, N, stream);
  } else {
    float* b256 = (float*)alloc((size_t)N * 256 * 4 + slackB);
    float* ba   = (float*)alloc((size_t)N * 128 * 4 + slackB);
    float* bb   = (float*)alloc((size_t)N * 128 * 4 + slackB);
    run_net<float>(x, t, W1, b1, W2, b2, W3, b3, W4, b4, F1, c1, F2, c2, F3, c3,
                   b256, ba, bb, rp, col, dinv,
                   nullptr, nullptr, false, out, N, stream);
  }
}